// Round 1
// baseline (7381.792 us; speedup 1.0000x reference)
//
#include <hip/hip_runtime.h>
#include <hip/hip_bf16.h>
#include <math.h>

// ---------------- GEMM1: h1 = x @ W1^T, plus s_src1/s_dst1 ----------------
// x:[N,128] W1:[64,128] -> h1:[N,64]; s1s/s1d:[N,4]
#define G1_NODES 32
__global__ __launch_bounds__(256) void gemm1_kernel(
    const float* __restrict__ x, const float* __restrict__ W1,
    const float* __restrict__ a_src, const float* __restrict__ a_dst,
    float* __restrict__ h1, float* __restrict__ s1s, float* __restrict__ s1d, int N)
{
    __shared__ float W1sT[128][65];          // transposed: W1sT[k][c] = W1[c*128+k]
    __shared__ float xs[G1_NODES][129];
    int tid = threadIdx.x;
    int nb = blockIdx.x * G1_NODES;

    for (int i = tid; i < 64 * 128; i += 256) {
        int c = i >> 7, k = i & 127;
        W1sT[k][c] = W1[i];
    }
    for (int i = tid; i < G1_NODES * 128; i += 256) {
        int nl = i >> 7, k = i & 127;
        int n = nb + nl;
        xs[nl][k] = (n < N) ? x[(size_t)n * 128 + k] : 0.f;
    }
    __syncthreads();

    int nl = tid >> 3;           // 0..31
    int c0 = (tid & 7) * 8;      // 0,8,...,56
    float acc[8] = {0.f,0.f,0.f,0.f,0.f,0.f,0.f,0.f};
    #pragma unroll 4
    for (int k = 0; k < 128; ++k) {
        float xv = xs[nl][k];
        #pragma unroll
        for (int j = 0; j < 8; ++j) acc[j] += xv * W1sT[k][c0 + j];
    }
    int n = nb + nl;
    if (n < N) {
        float4* p = (float4*)&h1[(size_t)n * 64 + c0];
        p[0] = make_float4(acc[0], acc[1], acc[2], acc[3]);
        p[1] = make_float4(acc[4], acc[5], acc[6], acc[7]);
    }
    // head = c0/16; the two threads covering one head are adjacent (tid^1)
    int head = (tid & 7) >> 1;
    int cb = c0 - head * 16;     // 0 or 8
    float ss = 0.f, sd = 0.f;
    #pragma unroll
    for (int j = 0; j < 8; ++j) {
        ss += acc[j] * a_src[head * 16 + cb + j];
        sd += acc[j] * a_dst[head * 16 + cb + j];
    }
    ss += __shfl_xor(ss, 1);
    sd += __shfl_xor(sd, 1);
    if (n < N && (tid & 1) == 0) {
        s1s[n * 4 + head] = ss;
        s1d[n * 4 + head] = sd;
    }
}

// ---------------- Edge pass 1: scatter w*h1[src] into acc1[dst] ----------------
// one thread per (edge, head); w = exp(leaky_relu(s_src[src]+s_dst[dst]))
__global__ __launch_bounds__(256) void edge1_kernel(
    const int* __restrict__ ei, const float* __restrict__ h1,
    const float* __restrict__ s1s, const float* __restrict__ s1d,
    float* __restrict__ acc1, float* __restrict__ den1, int E, int N)
{
    int gid = blockIdx.x * 256 + threadIdx.x;
    int e = gid >> 2;
    int head = gid & 3;
    if (e >= E + N) return;
    int src, dst;
    if (e < E) { src = ei[e]; dst = ei[E + e]; }
    else       { src = dst = e - E; }
    float s = s1s[src * 4 + head] + s1d[dst * 4 + head];
    s = (s >= 0.f) ? s : 0.2f * s;
    float w = __expf(s);
    atomicAdd(&den1[dst * 4 + head], w);
    const float4* hp = (const float4*)&h1[(size_t)src * 64 + head * 16];
    float* ap = &acc1[(size_t)dst * 64 + head * 16];
    #pragma unroll
    for (int q = 0; q < 4; ++q) {
        float4 v = hp[q];
        atomicAdd(&ap[q * 4 + 0], w * v.x);
        atomicAdd(&ap[q * 4 + 1], w * v.y);
        atomicAdd(&ap[q * 4 + 2], w * v.z);
        atomicAdd(&ap[q * 4 + 3], w * v.w);
    }
}

// ---------------- Normalize conv1 + bias + ELU (in place: acc1 -> x2) ----------------
__global__ __launch_bounds__(256) void norm1_kernel(
    float* __restrict__ acc1, const float* __restrict__ den1,
    const float* __restrict__ b1, int N)
{
    int i = blockIdx.x * 256 + threadIdx.x;
    if (i >= N * 64) return;
    int n = i >> 6, c = i & 63;
    float d = den1[n * 4 + (c >> 4)] + 1e-16f;
    float v = acc1[i] / d + b1[c];
    v = (v > 0.f) ? v : (__expf(v) - 1.f);
    acc1[i] = v;
}

// ---------------- GEMM2: h2 = x2 @ W2^T, plus s_src2/s_dst2 ----------------
// x2:[N,64] W2:[10,64] -> h2:[N,10]; s2s/s2d:[N]
__global__ __launch_bounds__(256) void gemm2_kernel(
    const float* __restrict__ x2, const float* __restrict__ W2,
    const float* __restrict__ a_src, const float* __restrict__ a_dst,
    float* __restrict__ h2, float* __restrict__ s2s, float* __restrict__ s2d, int N)
{
    __shared__ float w2s[640];
    for (int i = threadIdx.x; i < 640; i += 256) w2s[i] = W2[i];
    __syncthreads();
    int n = blockIdx.x * 256 + threadIdx.x;
    if (n >= N) return;
    float acc[10] = {0.f,0.f,0.f,0.f,0.f,0.f,0.f,0.f,0.f,0.f};
    const float4* xp = (const float4*)&x2[(size_t)n * 64];
    #pragma unroll
    for (int k4 = 0; k4 < 16; ++k4) {
        float4 xv = xp[k4];
        #pragma unroll
        for (int c = 0; c < 10; ++c) {
            const float* wr = &w2s[c * 64 + k4 * 4];
            acc[c] += xv.x * wr[0] + xv.y * wr[1] + xv.z * wr[2] + xv.w * wr[3];
        }
    }
    float ss = 0.f, sd = 0.f;
    #pragma unroll
    for (int c = 0; c < 10; ++c) {
        h2[(size_t)n * 10 + c] = acc[c];
        ss += acc[c] * a_src[c];
        sd += acc[c] * a_dst[c];
    }
    s2s[n] = ss;
    s2d[n] = sd;
}

// ---------------- Edge pass 2 ----------------
__global__ __launch_bounds__(256) void edge2_kernel(
    const int* __restrict__ ei, const float* __restrict__ h2,
    const float* __restrict__ s2s, const float* __restrict__ s2d,
    float* __restrict__ acc2, float* __restrict__ den2, int E, int N)
{
    int e = blockIdx.x * 256 + threadIdx.x;
    if (e >= E + N) return;
    int src, dst;
    if (e < E) { src = ei[e]; dst = ei[E + e]; }
    else       { src = dst = e - E; }
    float s = s2s[src] + s2d[dst];
    s = (s >= 0.f) ? s : 0.2f * s;
    float w = __expf(s);
    atomicAdd(&den2[dst], w);
    const float* hp = &h2[(size_t)src * 10];
    float* ap = &acc2[(size_t)dst * 10];
    #pragma unroll
    for (int c = 0; c < 10; ++c) atomicAdd(&ap[c], w * hp[c]);
}

// ---------------- Normalize conv2 + bias + pooled scatter ----------------
// batch is SORTED -> waves are (almost always) graph-uniform: wave-reduce then 1 atomic
__global__ __launch_bounds__(256) void pool_kernel(
    const float* __restrict__ acc2, const float* __restrict__ den2,
    const float* __restrict__ b2, const int* __restrict__ batch,
    float* __restrict__ pooled, float* __restrict__ cnt, int N)
{
    int n = blockIdx.x * 256 + threadIdx.x;
    bool active = n < N;
    int g = active ? batch[n] : -1;
    float vals[10];
    if (active) {
        float d = den2[n] + 1e-16f;
        #pragma unroll
        for (int c = 0; c < 10; ++c) vals[c] = acc2[(size_t)n * 10 + c] / d + b2[c];
    } else {
        #pragma unroll
        for (int c = 0; c < 10; ++c) vals[c] = 0.f;
    }
    int lane = threadIdx.x & 63;
    int g0 = __shfl(g, 0);
    bool uniform = __all(g == g0 || g < 0);
    if (uniform) {
        if (g0 >= 0) {
            #pragma unroll
            for (int c = 0; c < 10; ++c) {
                float v = vals[c];
                for (int o = 32; o > 0; o >>= 1) v += __shfl_down(v, o);
                if (lane == 0) atomicAdd(&pooled[g0 * 10 + c], v);
            }
            float one = active ? 1.f : 0.f;
            for (int o = 32; o > 0; o >>= 1) one += __shfl_down(one, o);
            if (lane == 0) atomicAdd(&cnt[g0], one);
        }
    } else if (active) {
        #pragma unroll
        for (int c = 0; c < 10; ++c) atomicAdd(&pooled[g * 10 + c], vals[c]);
        atomicAdd(&cnt[g], 1.f);
    }
}

// ---------------- Final: mean + log_softmax ----------------
__global__ void final_kernel(const float* __restrict__ pooled,
                             const float* __restrict__ cnt, float* __restrict__ out)
{
    int g = threadIdx.x;
    if (g >= 64) return;
    float c = cnt[g];
    if (c < 1.f) c = 1.f;
    float v[10], m = -1e30f;
    #pragma unroll
    for (int i = 0; i < 10; ++i) {
        v[i] = pooled[g * 10 + i] / c;
        m = fmaxf(m, v[i]);
    }
    float s = 0.f;
    #pragma unroll
    for (int i = 0; i < 10; ++i) s += __expf(v[i] - m);
    float lse = m + logf(s);
    #pragma unroll
    for (int i = 0; i < 10; ++i) out[g * 10 + i] = v[i] - lse;
}

extern "C" void kernel_launch(void* const* d_in, const int* in_sizes, int n_in,
                              void* d_out, int out_size, void* d_ws, size_t ws_size,
                              hipStream_t stream) {
    const float* x       = (const float*)d_in[0];
    const int*   ei      = (const int*)  d_in[1];
    const int*   batch   = (const int*)  d_in[2];
    const float* W1      = (const float*)d_in[3];
    const float* a_src1  = (const float*)d_in[4];
    const float* a_dst1  = (const float*)d_in[5];
    const float* b1      = (const float*)d_in[6];
    const float* W2      = (const float*)d_in[7];
    const float* a_src2  = (const float*)d_in[8];
    const float* a_dst2  = (const float*)d_in[9];
    const float* b2      = (const float*)d_in[10];
    float* out = (float*)d_out;

    int N = in_sizes[0] / 128;
    int E = in_sizes[1] / 2;

    float* f = (float*)d_ws;
    size_t off = 0;
    float* h1   = f + off; off += (size_t)N * 64;
    float* s1s  = f + off; off += (size_t)N * 4;
    float* s1d  = f + off; off += (size_t)N * 4;
    float* h2   = f + off; off += (size_t)N * 10;
    float* s2s  = f + off; off += (size_t)N;
    float* s2d  = f + off; off += (size_t)N;
    size_t zstart = off;
    float* acc1 = f + off; off += (size_t)N * 64;   // reused as x2 after norm1
    float* den1 = f + off; off += (size_t)N * 4;
    float* acc2 = f + off; off += (size_t)N * 10;
    float* den2 = f + off; off += (size_t)N;
    float* pooled = f + off; off += 64 * 10;
    float* cnt    = f + off; off += 64;

    // zero all accumulators (one async memset; graph-capturable)
    hipMemsetAsync((void*)(f + zstart), 0, (off - zstart) * sizeof(float), stream);

    int g1_blocks = (N + G1_NODES - 1) / G1_NODES;
    gemm1_kernel<<<g1_blocks, 256, 0, stream>>>(x, W1, a_src1, a_dst1, h1, s1s, s1d, N);

    int ne4 = (E + N) * 4;
    edge1_kernel<<<(ne4 + 255) / 256, 256, 0, stream>>>(ei, h1, s1s, s1d, acc1, den1, E, N);

    int n64 = N * 64;
    norm1_kernel<<<(n64 + 255) / 256, 256, 0, stream>>>(acc1, den1, b1, N);

    gemm2_kernel<<<(N + 255) / 256, 256, 0, stream>>>(acc1, W2, a_src2, a_dst2, h2, s2s, s2d, N);

    edge2_kernel<<<(E + N + 255) / 256, 256, 0, stream>>>(ei, h2, s2s, s2d, acc2, den2, E, N);

    pool_kernel<<<(N + 255) / 256, 256, 0, stream>>>(acc2, den2, b2, batch, pooled, cnt, N);

    final_kernel<<<1, 64, 0, stream>>>(pooled, cnt, out);
}

// Round 2
// 534.982 us; speedup vs baseline: 13.7982x; 13.7982x over previous
//
#include <hip/hip_runtime.h>
#include <hip/hip_bf16.h>
#include <math.h>

// ---------------- GEMM1: h1 = x @ W1^T, plus s_src1/s_dst1 ----------------
#define G1_NODES 32
__global__ __launch_bounds__(256) void gemm1_kernel(
    const float* __restrict__ x, const float* __restrict__ W1,
    const float* __restrict__ a_src, const float* __restrict__ a_dst,
    float* __restrict__ h1, float* __restrict__ s1s, float* __restrict__ s1d, int N)
{
    __shared__ float W1sT[128][65];
    __shared__ float xs[G1_NODES][129];
    int tid = threadIdx.x;
    int nb = blockIdx.x * G1_NODES;

    for (int i = tid; i < 64 * 128; i += 256) {
        int c = i >> 7, k = i & 127;
        W1sT[k][c] = W1[i];
    }
    for (int i = tid; i < G1_NODES * 128; i += 256) {
        int nl = i >> 7, k = i & 127;
        int n = nb + nl;
        xs[nl][k] = (n < N) ? x[(size_t)n * 128 + k] : 0.f;
    }
    __syncthreads();

    int nl = tid >> 3;
    int c0 = (tid & 7) * 8;
    float acc[8] = {0.f,0.f,0.f,0.f,0.f,0.f,0.f,0.f};
    #pragma unroll 4
    for (int k = 0; k < 128; ++k) {
        float xv = xs[nl][k];
        #pragma unroll
        for (int j = 0; j < 8; ++j) acc[j] += xv * W1sT[k][c0 + j];
    }
    int n = nb + nl;
    if (n < N) {
        float4* p = (float4*)&h1[(size_t)n * 64 + c0];
        p[0] = make_float4(acc[0], acc[1], acc[2], acc[3]);
        p[1] = make_float4(acc[4], acc[5], acc[6], acc[7]);
    }
    int head = (tid & 7) >> 1;
    int cb = c0 - head * 16;
    float ss = 0.f, sd = 0.f;
    #pragma unroll
    for (int j = 0; j < 8; ++j) {
        ss += acc[j] * a_src[head * 16 + cb + j];
        sd += acc[j] * a_dst[head * 16 + cb + j];
    }
    ss += __shfl_xor(ss, 1);
    sd += __shfl_xor(sd, 1);
    if (n < N && (tid & 1) == 0) {
        s1s[n * 4 + head] = ss;
        s1d[n * 4 + head] = sd;
    }
}

// ---------------- CSR build: count / scan / scatter ----------------
__global__ __launch_bounds__(256) void count_kernel(
    const int* __restrict__ ei, int* __restrict__ counts, int E)
{
    int e = blockIdx.x * 256 + threadIdx.x;
    if (e < E) atomicAdd(&counts[ei[E + e]], 1);
}

__global__ __launch_bounds__(256) void scan1_kernel(
    const int* __restrict__ counts, int* __restrict__ offs, int* __restrict__ bsum, int N)
{
    __shared__ int sh[256];
    int t = threadIdx.x;
    int i = blockIdx.x * 256 + t;
    int v = (i < N) ? counts[i] : 0;
    sh[t] = v; __syncthreads();
    for (int o = 1; o < 256; o <<= 1) {
        int u = (t >= o) ? sh[t - o] : 0;
        __syncthreads();
        sh[t] += u;
        __syncthreads();
    }
    if (i < N) offs[i] = sh[t] - v;          // local exclusive
    if (t == 255) bsum[blockIdx.x] = sh[255];
}

__global__ void scan2_kernel(int* __restrict__ bsum, int nb)
{
    if (threadIdx.x == 0 && blockIdx.x == 0) {
        int run = 0;
        for (int b = 0; b < nb; ++b) { int t = bsum[b]; bsum[b] = run; run += t; }
        bsum[nb] = run;
    }
}

__global__ __launch_bounds__(256) void scan3_kernel(
    int* __restrict__ offs, int* __restrict__ cursor, const int* __restrict__ bsum,
    int N, int nb)
{
    int i = blockIdx.x * 256 + threadIdx.x;
    if (i < N) {
        int v = offs[i] + bsum[blockIdx.x];
        offs[i] = v;
        cursor[i] = v;
    }
    if (i == 0) offs[N] = bsum[nb];
}

__global__ __launch_bounds__(256) void scatter_kernel(
    const int* __restrict__ ei, int* __restrict__ cursor, int* __restrict__ csr_src, int E)
{
    int e = blockIdx.x * 256 + threadIdx.x;
    if (e < E) {
        int dst = ei[E + e];
        int pos = atomicAdd(&cursor[dst], 1);
        csr_src[pos] = ei[e];
    }
}

// ---------------- Conv1 aggregation (gather) + normalize + bias + ELU ----------------
// one thread per (dst, head); self-loop folded in; no atomics
__global__ __launch_bounds__(256) void agg1_kernel(
    const int* __restrict__ offs, const int* __restrict__ csr_src,
    const float* __restrict__ h1, const float* __restrict__ s1s,
    const float* __restrict__ s1d, const float* __restrict__ b1,
    float* __restrict__ x2, int N)
{
    int tid = blockIdx.x * 256 + threadIdx.x;
    int n = tid >> 2, h = tid & 3;
    if (n >= N) return;
    float sdst = s1d[n * 4 + h];

    // self-loop term
    float s = s1s[n * 4 + h] + sdst;
    s = (s >= 0.f) ? s : 0.2f * s;
    float w = __expf(s);
    float den = w;
    float acc[16];
    {
        const float4* hp = (const float4*)&h1[(size_t)n * 64 + h * 16];
        #pragma unroll
        for (int q = 0; q < 4; ++q) {
            float4 v = hp[q];
            acc[q*4+0] = w * v.x; acc[q*4+1] = w * v.y;
            acc[q*4+2] = w * v.z; acc[q*4+3] = w * v.w;
        }
    }
    int row = offs[n], end = offs[n + 1];
    for (int i = row; i < end; ++i) {
        int src = csr_src[i];
        float ss = s1s[src * 4 + h] + sdst;
        ss = (ss >= 0.f) ? ss : 0.2f * ss;
        float we = __expf(ss);
        den += we;
        const float4* sp = (const float4*)&h1[(size_t)src * 64 + h * 16];
        #pragma unroll
        for (int q = 0; q < 4; ++q) {
            float4 v = sp[q];
            acc[q*4+0] += we * v.x; acc[q*4+1] += we * v.y;
            acc[q*4+2] += we * v.z; acc[q*4+3] += we * v.w;
        }
    }
    float inv = 1.f / (den + 1e-16f);
    float4* op = (float4*)&x2[(size_t)n * 64 + h * 16];
    #pragma unroll
    for (int q = 0; q < 4; ++q) {
        float4 o;
        float v0 = acc[q*4+0] * inv + b1[h*16 + q*4+0];
        float v1 = acc[q*4+1] * inv + b1[h*16 + q*4+1];
        float v2 = acc[q*4+2] * inv + b1[h*16 + q*4+2];
        float v3 = acc[q*4+3] * inv + b1[h*16 + q*4+3];
        o.x = (v0 > 0.f) ? v0 : (__expf(v0) - 1.f);
        o.y = (v1 > 0.f) ? v1 : (__expf(v1) - 1.f);
        o.z = (v2 > 0.f) ? v2 : (__expf(v2) - 1.f);
        o.w = (v3 > 0.f) ? v3 : (__expf(v3) - 1.f);
        op[q] = o;
    }
}

// ---------------- GEMM2: h2 = x2 @ W2^T, plus s_src2/s_dst2 ----------------
__global__ __launch_bounds__(256) void gemm2_kernel(
    const float* __restrict__ x2, const float* __restrict__ W2,
    const float* __restrict__ a_src, const float* __restrict__ a_dst,
    float* __restrict__ h2, float* __restrict__ s2s, float* __restrict__ s2d, int N)
{
    __shared__ float w2s[640];
    for (int i = threadIdx.x; i < 640; i += 256) w2s[i] = W2[i];
    __syncthreads();
    int n = blockIdx.x * 256 + threadIdx.x;
    if (n >= N) return;
    float acc[10] = {0.f,0.f,0.f,0.f,0.f,0.f,0.f,0.f,0.f,0.f};
    const float4* xp = (const float4*)&x2[(size_t)n * 64];
    #pragma unroll
    for (int k4 = 0; k4 < 16; ++k4) {
        float4 xv = xp[k4];
        #pragma unroll
        for (int c = 0; c < 10; ++c) {
            const float* wr = &w2s[c * 64 + k4 * 4];
            acc[c] += xv.x * wr[0] + xv.y * wr[1] + xv.z * wr[2] + xv.w * wr[3];
        }
    }
    float ss = 0.f, sd = 0.f;
    #pragma unroll
    for (int c = 0; c < 10; ++c) {
        h2[(size_t)n * 10 + c] = acc[c];
        ss += acc[c] * a_src[c];
        sd += acc[c] * a_dst[c];
    }
    s2s[n] = ss;
    s2d[n] = sd;
}

// ---------------- Conv2 aggregation (gather) + normalize + bias + pool ----------------
__global__ __launch_bounds__(256) void agg2_pool_kernel(
    const int* __restrict__ offs, const int* __restrict__ csr_src,
    const float* __restrict__ h2, const float* __restrict__ s2s,
    const float* __restrict__ s2d, const float* __restrict__ b2,
    const int* __restrict__ batch, float* __restrict__ pooled,
    float* __restrict__ cnt, int N)
{
    int n = blockIdx.x * 256 + threadIdx.x;
    bool active = n < N;
    float vals[10];
    int g = -1;
    if (active) {
        g = batch[n];
        float sdst = s2d[n];
        float s = s2s[n] + sdst;
        s = (s >= 0.f) ? s : 0.2f * s;
        float w = __expf(s);
        float den = w;
        float acc[10];
        {
            const float2* hp = (const float2*)&h2[(size_t)n * 10];
            #pragma unroll
            for (int q = 0; q < 5; ++q) {
                float2 v = hp[q];
                acc[q*2] = w * v.x; acc[q*2+1] = w * v.y;
            }
        }
        int row = offs[n], end = offs[n + 1];
        for (int i = row; i < end; ++i) {
            int src = csr_src[i];
            float ss = s2s[src] + sdst;
            ss = (ss >= 0.f) ? ss : 0.2f * ss;
            float we = __expf(ss);
            den += we;
            const float2* sp = (const float2*)&h2[(size_t)src * 10];
            #pragma unroll
            for (int q = 0; q < 5; ++q) {
                float2 v = sp[q];
                acc[q*2] += we * v.x; acc[q*2+1] += we * v.y;
            }
        }
        float inv = 1.f / (den + 1e-16f);
        #pragma unroll
        for (int c = 0; c < 10; ++c) vals[c] = acc[c] * inv + b2[c];
    } else {
        #pragma unroll
        for (int c = 0; c < 10; ++c) vals[c] = 0.f;
    }

    int lane = threadIdx.x & 63;
    int g0 = __shfl(g, 0);
    bool uniform = __all(g == g0 || g < 0);
    if (uniform) {
        if (g0 >= 0) {
            #pragma unroll
            for (int c = 0; c < 10; ++c) {
                float v = vals[c];
                for (int o = 32; o > 0; o >>= 1) v += __shfl_down(v, o);
                if (lane == 0) atomicAdd(&pooled[g0 * 10 + c], v);
            }
            float one = active ? 1.f : 0.f;
            for (int o = 32; o > 0; o >>= 1) one += __shfl_down(one, o);
            if (lane == 0) atomicAdd(&cnt[g0], one);
        }
    } else if (active) {
        #pragma unroll
        for (int c = 0; c < 10; ++c) atomicAdd(&pooled[g * 10 + c], vals[c]);
        atomicAdd(&cnt[g], 1.f);
    }
}

// ---------------- Final: mean + log_softmax ----------------
__global__ void final_kernel(const float* __restrict__ pooled,
                             const float* __restrict__ cnt, float* __restrict__ out)
{
    int g = threadIdx.x;
    if (g >= 64) return;
    float c = cnt[g];
    if (c < 1.f) c = 1.f;
    float v[10], m = -1e30f;
    #pragma unroll
    for (int i = 0; i < 10; ++i) {
        v[i] = pooled[g * 10 + i] / c;
        m = fmaxf(m, v[i]);
    }
    float s = 0.f;
    #pragma unroll
    for (int i = 0; i < 10; ++i) s += __expf(v[i] - m);
    float lse = m + logf(s);
    #pragma unroll
    for (int i = 0; i < 10; ++i) out[g * 10 + i] = v[i] - lse;
}

extern "C" void kernel_launch(void* const* d_in, const int* in_sizes, int n_in,
                              void* d_out, int out_size, void* d_ws, size_t ws_size,
                              hipStream_t stream) {
    const float* x       = (const float*)d_in[0];
    const int*   ei      = (const int*)  d_in[1];
    const int*   batch   = (const int*)  d_in[2];
    const float* W1      = (const float*)d_in[3];
    const float* a_src1  = (const float*)d_in[4];
    const float* a_dst1  = (const float*)d_in[5];
    const float* b1      = (const float*)d_in[6];
    const float* W2      = (const float*)d_in[7];
    const float* a_src2  = (const float*)d_in[8];
    const float* a_dst2  = (const float*)d_in[9];
    const float* b2      = (const float*)d_in[10];
    float* out = (float*)d_out;

    int N = in_sizes[0] / 128;
    int E = in_sizes[1] / 2;
    int nb = (N + 255) / 256;

    float* f = (float*)d_ws;
    size_t off = 0;
    float* h1   = f + off;            // [N,64]; h2 aliases this after agg1
    float* h2   = h1;                 // [N,10]  (alias — h1 dead after agg1)
    off += (size_t)N * 64;
    float* s1s  = f + off; float* s2s = s1s; off += (size_t)N * 4;  // s2s aliases
    float* s1d  = f + off; float* s2d = s1d; off += (size_t)N * 4;  // s2d aliases
    float* x2   = f + off; off += (size_t)N * 64;
    int* iw = (int*)(f + off);
    size_t ioff = 0;
    int* offs    = iw + ioff; ioff += (size_t)N + 1;
    int* cursor  = iw + ioff; ioff += (size_t)N;
    int* bsum    = iw + ioff; ioff += (size_t)nb + 1;
    int* csr_src = iw + ioff; ioff += (size_t)E;
    // zero region: counts[N] + pooled[640] + cnt[64], contiguous
    int*   counts = iw + ioff;
    float* pooled = (float*)(iw + ioff + N);
    float* cnt    = pooled + 640;

    hipMemsetAsync((void*)counts, 0, ((size_t)N + 704) * sizeof(int), stream);

    int g1_blocks = (N + G1_NODES - 1) / G1_NODES;
    gemm1_kernel<<<g1_blocks, 256, 0, stream>>>(x, W1, a_src1, a_dst1, h1, s1s, s1d, N);

    int eb = (E + 255) / 256;
    count_kernel<<<eb, 256, 0, stream>>>(ei, counts, E);
    scan1_kernel<<<nb, 256, 0, stream>>>(counts, offs, bsum, N);
    scan2_kernel<<<1, 64, 0, stream>>>(bsum, nb);
    scan3_kernel<<<nb, 256, 0, stream>>>(offs, cursor, bsum, N, nb);
    scatter_kernel<<<eb, 256, 0, stream>>>(ei, cursor, csr_src, E);

    agg1_kernel<<<(N * 4 + 255) / 256, 256, 0, stream>>>(
        offs, csr_src, h1, s1s, s1d, b1, x2, N);

    gemm2_kernel<<<(N + 255) / 256, 256, 0, stream>>>(x2, W2, a_src2, a_dst2, h2, s2s, s2d, N);

    agg2_pool_kernel<<<nb, 256, 0, stream>>>(
        offs, csr_src, h2, s2s, s2d, b2, batch, pooled, cnt, N);

    final_kernel<<<1, 64, 0, stream>>>(pooled, cnt, out);
}

// Round 3
// 366.122 us; speedup vs baseline: 20.1621x; 1.4612x over previous
//
#include <hip/hip_runtime.h>
#include <hip/hip_bf16.h>
#include <math.h>

#define BSHIFT 7
#define BWIDTH (1 << BSHIFT)       // 128 dst per bucket
#define A3_TILE 2048

// ---------------- GEMM1: h1 = x @ W1^T, plus s_src1/s_dst1 ----------------
#define G1_NODES 32
__global__ __launch_bounds__(256) void gemm1_kernel(
    const float* __restrict__ x, const float* __restrict__ W1,
    const float* __restrict__ a_src, const float* __restrict__ a_dst,
    float* __restrict__ h1, float* __restrict__ s1s, float* __restrict__ s1d, int N)
{
    __shared__ float W1sT[128][65];
    __shared__ float xs[G1_NODES][129];
    int tid = threadIdx.x;
    int nb = blockIdx.x * G1_NODES;

    for (int i = tid; i < 64 * 128; i += 256) {
        int c = i >> 7, k = i & 127;
        W1sT[k][c] = W1[i];
    }
    for (int i = tid; i < G1_NODES * 128; i += 256) {
        int nl = i >> 7, k = i & 127;
        int n = nb + nl;
        xs[nl][k] = (n < N) ? x[(size_t)n * 128 + k] : 0.f;
    }
    __syncthreads();

    int nl = tid >> 3;
    int c0 = (tid & 7) * 8;
    float acc[8] = {0.f,0.f,0.f,0.f,0.f,0.f,0.f,0.f};
    #pragma unroll 4
    for (int k = 0; k < 128; ++k) {
        float xv = xs[nl][k];
        #pragma unroll
        for (int j = 0; j < 8; ++j) acc[j] += xv * W1sT[k][c0 + j];
    }
    int n = nb + nl;
    if (n < N) {
        float4* p = (float4*)&h1[(size_t)n * 64 + c0];
        p[0] = make_float4(acc[0], acc[1], acc[2], acc[3]);
        p[1] = make_float4(acc[4], acc[5], acc[6], acc[7]);
    }
    int head = (tid & 7) >> 1;
    int cb = c0 - head * 16;
    float ss = 0.f, sd = 0.f;
    #pragma unroll
    for (int j = 0; j < 8; ++j) {
        ss += acc[j] * a_src[head * 16 + cb + j];
        sd += acc[j] * a_dst[head * 16 + cb + j];
    }
    ss += __shfl_xor(ss, 1);
    sd += __shfl_xor(sd, 1);
    if (n < N && (tid & 1) == 0) {
        s1s[n * 4 + head] = ss;
        s1d[n * 4 + head] = sd;
    }
}

// ---------------- A1: bucket histogram (LDS-staged) ----------------
__global__ __launch_bounds__(256) void bhist_kernel(
    const int* __restrict__ ei, int* __restrict__ bhist, int E, int NBK)
{
    __shared__ int h[1024];
    for (int i = threadIdx.x; i < 1024; i += 256) h[i] = 0;
    __syncthreads();
    int stride = gridDim.x * 256;
    for (int e = blockIdx.x * 256 + threadIdx.x; e < E; e += stride)
        atomicAdd(&h[ei[E + e] >> BSHIFT], 1);
    __syncthreads();
    for (int b = threadIdx.x; b < NBK; b += 256) {
        int c = h[b];
        if (c) atomicAdd(&bhist[b], c);
    }
}

// ---------------- A2: exclusive scan over buckets -> bb, bcur ----------------
__global__ __launch_bounds__(1024) void bscan_kernel(
    const int* __restrict__ bhist, int* __restrict__ bb, int* __restrict__ bcur, int NBK)
{
    __shared__ int sh[1024];
    int t = threadIdx.x;
    int v = (t < NBK) ? bhist[t] : 0;
    sh[t] = v;
    __syncthreads();
    for (int o = 1; o < 1024; o <<= 1) {
        int u = (t >= o) ? sh[t - o] : 0;
        __syncthreads();
        sh[t] += u;
        __syncthreads();
    }
    int incl = sh[t];
    int excl = incl - v;
    if (t < NBK) { bb[t] = excl; bcur[t] = excl; }
    if (t == NBK - 1) bb[NBK] = incl;
}

// ---------------- A3: partition edges into bucket regions (packed) ----------------
// pack = ((dst & 127) << 17) | src   (src < 2^17)
__global__ __launch_bounds__(256) void partition_kernel(
    const int* __restrict__ ei, int* __restrict__ bcur, int* __restrict__ pairs,
    int E, int NBK)
{
    __shared__ int hist[1024];
    __shared__ int scanb[1024];
    __shared__ int gbase[1024];
    __shared__ int partial[256];
    __shared__ int stage_pack[A3_TILE];
    __shared__ int stage_pos[A3_TILE];
    int t = threadIdx.x;
    int e0 = blockIdx.x * A3_TILE;
    for (int i = t; i < 1024; i += 256) hist[i] = 0;
    __syncthreads();
    int my_b[8], my_rank[8], my_pack[8];
    #pragma unroll
    for (int j = 0; j < 8; ++j) {
        int e = e0 + j * 256 + t;
        int b = -1, pack = 0, r = 0;
        if (e < E) {
            int s = ei[e], d = ei[E + e];
            b = d >> BSHIFT;
            pack = ((d & (BWIDTH - 1)) << 17) | s;
            r = atomicAdd(&hist[b], 1);
        }
        my_b[j] = b; my_pack[j] = pack; my_rank[j] = r;
    }
    __syncthreads();
    // blocked exclusive scan of hist[0..1023]: 4 per thread + Hillis-Steele
    int b4 = t * 4;
    int h0 = hist[b4], h1v = hist[b4 + 1], h2v = hist[b4 + 2], h3v = hist[b4 + 3];
    int tot = h0 + h1v + h2v + h3v;
    partial[t] = tot;
    __syncthreads();
    for (int o = 1; o < 256; o <<= 1) {
        int u = (t >= o) ? partial[t - o] : 0;
        __syncthreads();
        partial[t] += u;
        __syncthreads();
    }
    int excl = partial[t] - tot;
    scanb[b4]     = excl;
    scanb[b4 + 1] = excl + h0;
    scanb[b4 + 2] = excl + h0 + h1v;
    scanb[b4 + 3] = excl + h0 + h1v + h2v;
    int nvalid = partial[255];
    // reserve global space per bucket
    for (int b = t; b < NBK; b += 256) {
        int c = hist[b];
        if (c > 0) gbase[b] = atomicAdd(&bcur[b], c);
    }
    __syncthreads();
    // stage ordered by bucket (coalesced output)
    #pragma unroll
    for (int j = 0; j < 8; ++j) {
        int b = my_b[j];
        if (b >= 0) {
            int slot = scanb[b] + my_rank[j];
            stage_pack[slot] = my_pack[j];
            stage_pos[slot]  = gbase[b] + my_rank[j];
        }
    }
    __syncthreads();
    for (int i = t; i < nvalid; i += 256)
        pairs[stage_pos[i]] = stage_pack[i];
}

// ---------------- B1: per-dst offs directly from bucket (no global scan) ----------------
__global__ __launch_bounds__(128) void offs_kernel(
    const int* __restrict__ pairs, const int* __restrict__ bb,
    int* __restrict__ offs, int N, int NBK, int E)
{
    int b = blockIdx.x;
    __shared__ int hist[BWIDTH];
    int t = threadIdx.x;
    hist[t] = 0;
    __syncthreads();
    int s = bb[b], e = bb[b + 1];
    for (int i = s + t; i < e; i += 128)
        atomicAdd(&hist[(pairs[i] >> 17) & (BWIDTH - 1)], 1);
    __syncthreads();
    int v = hist[t];
    for (int o = 1; o < BWIDTH; o <<= 1) {
        int u = (t >= o) ? hist[t - o] : 0;
        __syncthreads();
        hist[t] += u;
        __syncthreads();
    }
    int excl = hist[t] - v;
    int dst = b * BWIDTH + t;
    if (dst < N) offs[dst] = s + excl;
    if (b == 0 && t == 0) offs[N] = E;
}

// ---------------- B2: scatter src into CSR, LDS cursors, L2-local window ----------------
__global__ __launch_bounds__(128) void scat_kernel(
    const int* __restrict__ pairs, const int* __restrict__ bb,
    const int* __restrict__ offs, int* __restrict__ csr_src, int N)
{
    int b = blockIdx.x;
    __shared__ int cur[BWIDTH];
    int t = threadIdx.x;
    int dst = b * BWIDTH + t;
    cur[t] = (dst < N) ? offs[dst] : 0;
    __syncthreads();
    int s = bb[b], e = bb[b + 1];
    for (int i = s + t; i < e; i += 128) {
        int p = pairs[i];
        int pos = atomicAdd(&cur[(p >> 17) & (BWIDTH - 1)], 1);
        csr_src[pos] = p & 0x1FFFF;
    }
}

// ---------------- Conv1 aggregation (gather) + normalize + bias + ELU ----------------
__global__ __launch_bounds__(256) void agg1_kernel(
    const int* __restrict__ offs, const int* __restrict__ csr_src,
    const float* __restrict__ h1, const float* __restrict__ s1s,
    const float* __restrict__ s1d, const float* __restrict__ b1,
    float* __restrict__ x2, int N)
{
    int tid = blockIdx.x * 256 + threadIdx.x;
    int n = tid >> 2, h = tid & 3;
    if (n >= N) return;
    float sdst = s1d[n * 4 + h];

    float s = s1s[n * 4 + h] + sdst;
    s = (s >= 0.f) ? s : 0.2f * s;
    float w = __expf(s);
    float den = w;
    float acc[16];
    {
        const float4* hp = (const float4*)&h1[(size_t)n * 64 + h * 16];
        #pragma unroll
        for (int q = 0; q < 4; ++q) {
            float4 v = hp[q];
            acc[q*4+0] = w * v.x; acc[q*4+1] = w * v.y;
            acc[q*4+2] = w * v.z; acc[q*4+3] = w * v.w;
        }
    }
    int row = offs[n], end = offs[n + 1];
    for (int i = row; i < end; ++i) {
        int src = csr_src[i];
        float ss = s1s[src * 4 + h] + sdst;
        ss = (ss >= 0.f) ? ss : 0.2f * ss;
        float we = __expf(ss);
        den += we;
        const float4* sp = (const float4*)&h1[(size_t)src * 64 + h * 16];
        #pragma unroll
        for (int q = 0; q < 4; ++q) {
            float4 v = sp[q];
            acc[q*4+0] += we * v.x; acc[q*4+1] += we * v.y;
            acc[q*4+2] += we * v.z; acc[q*4+3] += we * v.w;
        }
    }
    float inv = 1.f / (den + 1e-16f);
    float4* op = (float4*)&x2[(size_t)n * 64 + h * 16];
    #pragma unroll
    for (int q = 0; q < 4; ++q) {
        float4 o;
        float v0 = acc[q*4+0] * inv + b1[h*16 + q*4+0];
        float v1 = acc[q*4+1] * inv + b1[h*16 + q*4+1];
        float v2 = acc[q*4+2] * inv + b1[h*16 + q*4+2];
        float v3 = acc[q*4+3] * inv + b1[h*16 + q*4+3];
        o.x = (v0 > 0.f) ? v0 : (__expf(v0) - 1.f);
        o.y = (v1 > 0.f) ? v1 : (__expf(v1) - 1.f);
        o.z = (v2 > 0.f) ? v2 : (__expf(v2) - 1.f);
        o.w = (v3 > 0.f) ? v3 : (__expf(v3) - 1.f);
        op[q] = o;
    }
}

// ---------------- GEMM2: h2 = x2 @ W2^T, plus s_src2/s_dst2 ----------------
__global__ __launch_bounds__(256) void gemm2_kernel(
    const float* __restrict__ x2, const float* __restrict__ W2,
    const float* __restrict__ a_src, const float* __restrict__ a_dst,
    float* __restrict__ h2, float* __restrict__ s2s, float* __restrict__ s2d, int N)
{
    __shared__ float w2s[640];
    for (int i = threadIdx.x; i < 640; i += 256) w2s[i] = W2[i];
    __syncthreads();
    int n = blockIdx.x * 256 + threadIdx.x;
    if (n >= N) return;
    float acc[10] = {0.f,0.f,0.f,0.f,0.f,0.f,0.f,0.f,0.f,0.f};
    const float4* xp = (const float4*)&x2[(size_t)n * 64];
    #pragma unroll
    for (int k4 = 0; k4 < 16; ++k4) {
        float4 xv = xp[k4];
        #pragma unroll
        for (int c = 0; c < 10; ++c) {
            const float* wr = &w2s[c * 64 + k4 * 4];
            acc[c] += xv.x * wr[0] + xv.y * wr[1] + xv.z * wr[2] + xv.w * wr[3];
        }
    }
    float ss = 0.f, sd = 0.f;
    #pragma unroll
    for (int c = 0; c < 10; ++c) {
        h2[(size_t)n * 10 + c] = acc[c];
        ss += acc[c] * a_src[c];
        sd += acc[c] * a_dst[c];
    }
    s2s[n] = ss;
    s2d[n] = sd;
}

// ---------------- Conv2 aggregation (gather) + normalize + bias + pool ----------------
__global__ __launch_bounds__(256) void agg2_pool_kernel(
    const int* __restrict__ offs, const int* __restrict__ csr_src,
    const float* __restrict__ h2, const float* __restrict__ s2s,
    const float* __restrict__ s2d, const float* __restrict__ b2,
    const int* __restrict__ batch, float* __restrict__ pooled,
    float* __restrict__ cnt, int N)
{
    int n = blockIdx.x * 256 + threadIdx.x;
    bool active = n < N;
    float vals[10];
    int g = -1;
    if (active) {
        g = batch[n];
        float sdst = s2d[n];
        float s = s2s[n] + sdst;
        s = (s >= 0.f) ? s : 0.2f * s;
        float w = __expf(s);
        float den = w;
        float acc[10];
        {
            const float2* hp = (const float2*)&h2[(size_t)n * 10];
            #pragma unroll
            for (int q = 0; q < 5; ++q) {
                float2 v = hp[q];
                acc[q*2] = w * v.x; acc[q*2+1] = w * v.y;
            }
        }
        int row = offs[n], end = offs[n + 1];
        for (int i = row; i < end; ++i) {
            int src = csr_src[i];
            float ss = s2s[src] + sdst;
            ss = (ss >= 0.f) ? ss : 0.2f * ss;
            float we = __expf(ss);
            den += we;
            const float2* sp = (const float2*)&h2[(size_t)src * 10];
            #pragma unroll
            for (int q = 0; q < 5; ++q) {
                float2 v = sp[q];
                acc[q*2] += we * v.x; acc[q*2+1] += we * v.y;
            }
        }
        float inv = 1.f / (den + 1e-16f);
        #pragma unroll
        for (int c = 0; c < 10; ++c) vals[c] = acc[c] * inv + b2[c];
    } else {
        #pragma unroll
        for (int c = 0; c < 10; ++c) vals[c] = 0.f;
    }

    int lane = threadIdx.x & 63;
    int g0 = __shfl(g, 0);
    bool uniform = __all(g == g0 || g < 0);
    if (uniform) {
        if (g0 >= 0) {
            #pragma unroll
            for (int c = 0; c < 10; ++c) {
                float v = vals[c];
                for (int o = 32; o > 0; o >>= 1) v += __shfl_down(v, o);
                if (lane == 0) atomicAdd(&pooled[g0 * 10 + c], v);
            }
            float one = active ? 1.f : 0.f;
            for (int o = 32; o > 0; o >>= 1) one += __shfl_down(one, o);
            if (lane == 0) atomicAdd(&cnt[g0], one);
        }
    } else if (active) {
        #pragma unroll
        for (int c = 0; c < 10; ++c) atomicAdd(&pooled[g * 10 + c], vals[c]);
        atomicAdd(&cnt[g], 1.f);
    }
}

// ---------------- Final: mean + log_softmax ----------------
__global__ void final_kernel(const float* __restrict__ pooled,
                             const float* __restrict__ cnt, float* __restrict__ out)
{
    int g = threadIdx.x;
    if (g >= 64) return;
    float c = cnt[g];
    if (c < 1.f) c = 1.f;
    float v[10], m = -1e30f;
    #pragma unroll
    for (int i = 0; i < 10; ++i) {
        v[i] = pooled[g * 10 + i] / c;
        m = fmaxf(m, v[i]);
    }
    float s = 0.f;
    #pragma unroll
    for (int i = 0; i < 10; ++i) s += __expf(v[i] - m);
    float lse = m + logf(s);
    #pragma unroll
    for (int i = 0; i < 10; ++i) out[g * 10 + i] = v[i] - lse;
}

extern "C" void kernel_launch(void* const* d_in, const int* in_sizes, int n_in,
                              void* d_out, int out_size, void* d_ws, size_t ws_size,
                              hipStream_t stream) {
    const float* x       = (const float*)d_in[0];
    const int*   ei      = (const int*)  d_in[1];
    const int*   batch   = (const int*)  d_in[2];
    const float* W1      = (const float*)d_in[3];
    const float* a_src1  = (const float*)d_in[4];
    const float* a_dst1  = (const float*)d_in[5];
    const float* b1      = (const float*)d_in[6];
    const float* W2      = (const float*)d_in[7];
    const float* a_src2  = (const float*)d_in[8];
    const float* a_dst2  = (const float*)d_in[9];
    const float* b2      = (const float*)d_in[10];
    float* out = (float*)d_out;

    int N = in_sizes[0] / 128;
    int E = in_sizes[1] / 2;
    int NBK = (N + BWIDTH - 1) >> BSHIFT;

    float* f = (float*)d_ws;
    size_t off = 0;
    float* h1   = f + off;            // [N,64]; h2 aliases (h1 dead after agg1)
    float* h2   = h1;
    off += (size_t)N * 64;
    float* s1s  = f + off; float* s2s = s1s; off += (size_t)N * 4;
    float* s1d  = f + off; float* s2d = s1d; off += (size_t)N * 4;
    // R1: pairs (E ints, live A3..B2) then x2 (N*64 floats, live agg1..gemm2)
    float* x2   = f + off;
    int*  pairs = (int*)x2;
    off += (size_t)N * 64;
    int* iw = (int*)(f + off);
    size_t ioff = 0;
    int* offs    = iw + ioff; ioff += (size_t)N + 1;
    int* csr_src = iw + ioff; ioff += (size_t)E;
    int* bb      = iw + ioff; ioff += (size_t)NBK + 1;
    int* bcur    = iw + ioff; ioff += (size_t)NBK;
    // zero region: bhist[NBK] + pooled[640] + cnt[64], contiguous
    int*   bhist  = iw + ioff;
    float* pooled = (float*)(iw + ioff + NBK);
    float* cnt    = pooled + 640;

    hipMemsetAsync((void*)bhist, 0, ((size_t)NBK + 704) * sizeof(int), stream);

    int g1_blocks = (N + G1_NODES - 1) / G1_NODES;
    gemm1_kernel<<<g1_blocks, 256, 0, stream>>>(x, W1, a_src1, a_dst1, h1, s1s, s1d, N);

    bhist_kernel<<<256, 256, 0, stream>>>(ei, bhist, E, NBK);
    bscan_kernel<<<1, 1024, 0, stream>>>(bhist, bb, bcur, NBK);
    int ntiles = (E + A3_TILE - 1) / A3_TILE;
    partition_kernel<<<ntiles, 256, 0, stream>>>(ei, bcur, pairs, E, NBK);
    offs_kernel<<<NBK, 128, 0, stream>>>(pairs, bb, offs, N, NBK, E);
    scat_kernel<<<NBK, 128, 0, stream>>>(pairs, bb, offs, csr_src, N);

    agg1_kernel<<<(N * 4 + 255) / 256, 256, 0, stream>>>(
        offs, csr_src, h1, s1s, s1d, b1, x2, N);

    gemm2_kernel<<<(N + 255) / 256, 256, 0, stream>>>(x2, W2, a_src2, a_dst2, h2, s2s, s2d, N);

    agg2_pool_kernel<<<(N + 255) / 256, 256, 0, stream>>>(
        offs, csr_src, h2, s2s, s2d, b2, batch, pooled, cnt, N);

    final_kernel<<<1, 64, 0, stream>>>(pooled, cnt, out);
}

// Round 4
// 329.930 us; speedup vs baseline: 22.3738x; 1.1097x over previous
//
#include <hip/hip_runtime.h>
#include <hip/hip_bf16.h>
#include <math.h>

#define BSHIFT 7
#define BWIDTH (1 << BSHIFT)       // 128 dst per bucket
#define A3_TILE 2048

// ---------------- GEMM1: h1 = x @ W1^T, plus s_src1/s_dst1 ----------------
// register-tiled 8x8: block = 256 nodes x 64 ch, K-chunks of 16
#define G1_TN 256
#define G1_KC 16
__global__ __launch_bounds__(256) void gemm1_kernel(
    const float* __restrict__ x, const float* __restrict__ W1,
    const float* __restrict__ a_src, const float* __restrict__ a_dst,
    float* __restrict__ h1, float* __restrict__ s1s, float* __restrict__ s1d, int N)
{
    __shared__ float Ws[128 * 64];      // Ws[k*64+c] = W1[c*128+k]
    __shared__ float xs[G1_KC][260];    // xs[kk][node_local], 16B-aligned rows
    int tid = threadIdx.x;
    int nb = blockIdx.x * G1_TN;

    // W transpose load (one-time, 32 KB, L2-hot across blocks)
    for (int i = tid; i < 64 * 128; i += 256) {
        int k = i >> 6, c = i & 63;
        Ws[i] = W1[c * 128 + k];
    }

    int ng = tid & 31;           // node-quad id
    int cg = tid >> 5;           // channel-group (8 ch)
    int c0 = cg * 8;
    float acc[8][8];
    #pragma unroll
    for (int q = 0; q < 8; ++q)
        #pragma unroll
        for (int j = 0; j < 8; ++j) acc[q][j] = 0.f;

    for (int kc = 0; kc < 128; kc += G1_KC) {
        __syncthreads();
        // stage x chunk transposed: xs[kk][nl]; coalesced float4 global reads
        #pragma unroll
        for (int r = 0; r < 4; ++r) {
            int i4 = tid + r * 256;
            int nl = i4 >> 2;              // 0..255
            int kk4 = (i4 & 3) * 4;        // 0,4,8,12
            int n = nb + nl;
            float4 v = (n < N) ? *(const float4*)&x[(size_t)n * 128 + kc + kk4]
                               : make_float4(0.f, 0.f, 0.f, 0.f);
            xs[kk4 + 0][nl] = v.x;
            xs[kk4 + 1][nl] = v.y;
            xs[kk4 + 2][nl] = v.z;
            xs[kk4 + 3][nl] = v.w;
        }
        __syncthreads();
        #pragma unroll
        for (int kk = 0; kk < G1_KC; ++kk) {
            float4 xa = *(const float4*)&xs[kk][ng * 4];
            float4 xb = *(const float4*)&xs[kk][128 + ng * 4];
            const float* wr = &Ws[(kc + kk) * 64 + c0];
            float4 w0 = *(const float4*)&wr[0];
            float4 w1 = *(const float4*)&wr[4];
            float xv[8] = {xa.x, xa.y, xa.z, xa.w, xb.x, xb.y, xb.z, xb.w};
            float wv[8] = {w0.x, w0.y, w0.z, w0.w, w1.x, w1.y, w1.z, w1.w};
            #pragma unroll
            for (int q = 0; q < 8; ++q)
                #pragma unroll
                for (int j = 0; j < 8; ++j)
                    acc[q][j] += xv[q] * wv[j];
        }
    }

    #pragma unroll
    for (int q = 0; q < 8; ++q) {
        int nl = (q < 4) ? (ng * 4 + q) : (128 + ng * 4 + (q - 4));
        int n = nb + nl;
        float ss = 0.f, sd = 0.f;
        #pragma unroll
        for (int j = 0; j < 8; ++j) {
            ss += acc[q][j] * a_src[c0 + j];
            sd += acc[q][j] * a_dst[c0 + j];
        }
        ss += __shfl_xor(ss, 32);    // combine cg pair -> full 16-ch head sum
        sd += __shfl_xor(sd, 32);
        if (n < N) {
            *(float4*)&h1[(size_t)n * 64 + c0] =
                make_float4(acc[q][0], acc[q][1], acc[q][2], acc[q][3]);
            *(float4*)&h1[(size_t)n * 64 + c0 + 4] =
                make_float4(acc[q][4], acc[q][5], acc[q][6], acc[q][7]);
            if ((cg & 1) == 0) {
                s1s[n * 4 + (cg >> 1)] = ss;
                s1d[n * 4 + (cg >> 1)] = sd;
            }
        }
    }
}

// ---------------- A1: bucket histogram (LDS-staged) ----------------
__global__ __launch_bounds__(256) void bhist_kernel(
    const int* __restrict__ ei, int* __restrict__ bhist, int E, int NBK)
{
    __shared__ int h[1024];
    for (int i = threadIdx.x; i < 1024; i += 256) h[i] = 0;
    __syncthreads();
    int stride = gridDim.x * 256;
    for (int e = blockIdx.x * 256 + threadIdx.x; e < E; e += stride)
        atomicAdd(&h[ei[E + e] >> BSHIFT], 1);
    __syncthreads();
    for (int b = threadIdx.x; b < NBK; b += 256) {
        int c = h[b];
        if (c) atomicAdd(&bhist[b], c);
    }
}

// ---------------- A2: exclusive scan over buckets -> bb, bcur ----------------
__global__ __launch_bounds__(1024) void bscan_kernel(
    const int* __restrict__ bhist, int* __restrict__ bb, int* __restrict__ bcur, int NBK)
{
    __shared__ int sh[1024];
    int t = threadIdx.x;
    int v = (t < NBK) ? bhist[t] : 0;
    sh[t] = v;
    __syncthreads();
    for (int o = 1; o < 1024; o <<= 1) {
        int u = (t >= o) ? sh[t - o] : 0;
        __syncthreads();
        sh[t] += u;
        __syncthreads();
    }
    int incl = sh[t];
    int excl = incl - v;
    if (t < NBK) { bb[t] = excl; bcur[t] = excl; }
    if (t == NBK - 1) bb[NBK] = incl;
}

// ---------------- A3: partition edges into bucket regions (packed) ----------------
// pack = ((dst & 127) << 17) | src   (src < 2^17)
__global__ __launch_bounds__(256) void partition_kernel(
    const int* __restrict__ ei, int* __restrict__ bcur, int* __restrict__ pairs,
    int E, int NBK)
{
    __shared__ int hist[1024];
    __shared__ int scanb[1024];
    __shared__ int gbase[1024];
    __shared__ int partial[256];
    __shared__ int stage_pack[A3_TILE];
    __shared__ int stage_pos[A3_TILE];
    int t = threadIdx.x;
    int e0 = blockIdx.x * A3_TILE;
    for (int i = t; i < 1024; i += 256) hist[i] = 0;
    __syncthreads();
    int my_b[8], my_rank[8], my_pack[8];
    #pragma unroll
    for (int j = 0; j < 8; ++j) {
        int e = e0 + j * 256 + t;
        int b = -1, pack = 0, r = 0;
        if (e < E) {
            int s = ei[e], d = ei[E + e];
            b = d >> BSHIFT;
            pack = ((d & (BWIDTH - 1)) << 17) | s;
            r = atomicAdd(&hist[b], 1);
        }
        my_b[j] = b; my_pack[j] = pack; my_rank[j] = r;
    }
    __syncthreads();
    int b4 = t * 4;
    int h0 = hist[b4], h1v = hist[b4 + 1], h2v = hist[b4 + 2], h3v = hist[b4 + 3];
    int tot = h0 + h1v + h2v + h3v;
    partial[t] = tot;
    __syncthreads();
    for (int o = 1; o < 256; o <<= 1) {
        int u = (t >= o) ? partial[t - o] : 0;
        __syncthreads();
        partial[t] += u;
        __syncthreads();
    }
    int excl = partial[t] - tot;
    scanb[b4]     = excl;
    scanb[b4 + 1] = excl + h0;
    scanb[b4 + 2] = excl + h0 + h1v;
    scanb[b4 + 3] = excl + h0 + h1v + h2v;
    int nvalid = partial[255];
    for (int b = t; b < NBK; b += 256) {
        int c = hist[b];
        if (c > 0) gbase[b] = atomicAdd(&bcur[b], c);
    }
    __syncthreads();
    #pragma unroll
    for (int j = 0; j < 8; ++j) {
        int b = my_b[j];
        if (b >= 0) {
            int slot = scanb[b] + my_rank[j];
            stage_pack[slot] = my_pack[j];
            stage_pos[slot]  = gbase[b] + my_rank[j];
        }
    }
    __syncthreads();
    for (int i = t; i < nvalid; i += 256)
        pairs[stage_pos[i]] = stage_pack[i];
}

// ---------------- B1: per-dst offs directly from bucket ----------------
__global__ __launch_bounds__(128) void offs_kernel(
    const int* __restrict__ pairs, const int* __restrict__ bb,
    int* __restrict__ offs, int N, int NBK, int E)
{
    int b = blockIdx.x;
    __shared__ int hist[BWIDTH];
    int t = threadIdx.x;
    hist[t] = 0;
    __syncthreads();
    int s = bb[b], e = bb[b + 1];
    for (int i = s + t; i < e; i += 128)
        atomicAdd(&hist[(pairs[i] >> 17) & (BWIDTH - 1)], 1);
    __syncthreads();
    int v = hist[t];
    for (int o = 1; o < BWIDTH; o <<= 1) {
        int u = (t >= o) ? hist[t - o] : 0;
        __syncthreads();
        hist[t] += u;
        __syncthreads();
    }
    int excl = hist[t] - v;
    int dst = b * BWIDTH + t;
    if (dst < N) offs[dst] = s + excl;
    if (b == 0 && t == 0) offs[N] = E;
}

// ---------------- B2: scatter src into CSR, LDS cursors ----------------
__global__ __launch_bounds__(128) void scat_kernel(
    const int* __restrict__ pairs, const int* __restrict__ bb,
    const int* __restrict__ offs, int* __restrict__ csr_src, int N)
{
    int b = blockIdx.x;
    __shared__ int cur[BWIDTH];
    int t = threadIdx.x;
    int dst = b * BWIDTH + t;
    cur[t] = (dst < N) ? offs[dst] : 0;
    __syncthreads();
    int s = bb[b], e = bb[b + 1];
    for (int i = s + t; i < e; i += 128) {
        int p = pairs[i];
        int pos = atomicAdd(&cur[(p >> 17) & (BWIDTH - 1)], 1);
        csr_src[pos] = p & 0x1FFFF;
    }
}

// ---------------- Conv1 aggregation (gather) + normalize + bias + ELU ----------------
__global__ __launch_bounds__(256) void agg1_kernel(
    const int* __restrict__ offs, const int* __restrict__ csr_src,
    const float* __restrict__ h1, const float* __restrict__ s1s,
    const float* __restrict__ s1d, const float* __restrict__ b1,
    float* __restrict__ x2, int N)
{
    int tid = blockIdx.x * 256 + threadIdx.x;
    int n = tid >> 2, h = tid & 3;
    if (n >= N) return;
    float sdst = s1d[n * 4 + h];

    float s = s1s[n * 4 + h] + sdst;
    s = (s >= 0.f) ? s : 0.2f * s;
    float w = __expf(s);
    float den = w;
    float acc[16];
    {
        const float4* hp = (const float4*)&h1[(size_t)n * 64 + h * 16];
        #pragma unroll
        for (int q = 0; q < 4; ++q) {
            float4 v = hp[q];
            acc[q*4+0] = w * v.x; acc[q*4+1] = w * v.y;
            acc[q*4+2] = w * v.z; acc[q*4+3] = w * v.w;
        }
    }
    int row = offs[n], end = offs[n + 1];
    for (int i = row; i < end; ++i) {
        int src = csr_src[i];
        float ss = s1s[src * 4 + h] + sdst;
        ss = (ss >= 0.f) ? ss : 0.2f * ss;
        float we = __expf(ss);
        den += we;
        const float4* sp = (const float4*)&h1[(size_t)src * 64 + h * 16];
        #pragma unroll
        for (int q = 0; q < 4; ++q) {
            float4 v = sp[q];
            acc[q*4+0] += we * v.x; acc[q*4+1] += we * v.y;
            acc[q*4+2] += we * v.z; acc[q*4+3] += we * v.w;
        }
    }
    float inv = 1.f / (den + 1e-16f);
    float4* op = (float4*)&x2[(size_t)n * 64 + h * 16];
    #pragma unroll
    for (int q = 0; q < 4; ++q) {
        float4 o;
        float v0 = acc[q*4+0] * inv + b1[h*16 + q*4+0];
        float v1 = acc[q*4+1] * inv + b1[h*16 + q*4+1];
        float v2 = acc[q*4+2] * inv + b1[h*16 + q*4+2];
        float v3 = acc[q*4+3] * inv + b1[h*16 + q*4+3];
        o.x = (v0 > 0.f) ? v0 : (__expf(v0) - 1.f);
        o.y = (v1 > 0.f) ? v1 : (__expf(v1) - 1.f);
        o.z = (v2 > 0.f) ? v2 : (__expf(v2) - 1.f);
        o.w = (v3 > 0.f) ? v3 : (__expf(v3) - 1.f);
        op[q] = o;
    }
}

// ---------------- GEMM2: h2 = x2 @ W2^T, plus s_src2/s_dst2 ----------------
__global__ __launch_bounds__(256) void gemm2_kernel(
    const float* __restrict__ x2, const float* __restrict__ W2,
    const float* __restrict__ a_src, const float* __restrict__ a_dst,
    float* __restrict__ h2, float* __restrict__ s2s, float* __restrict__ s2d, int N)
{
    __shared__ float w2s[640];
    for (int i = threadIdx.x; i < 640; i += 256) w2s[i] = W2[i];
    __syncthreads();
    int n = blockIdx.x * 256 + threadIdx.x;
    if (n >= N) return;
    float acc[10] = {0.f,0.f,0.f,0.f,0.f,0.f,0.f,0.f,0.f,0.f};
    const float4* xp = (const float4*)&x2[(size_t)n * 64];
    #pragma unroll
    for (int k4 = 0; k4 < 16; ++k4) {
        float4 xv = xp[k4];
        #pragma unroll
        for (int c = 0; c < 10; ++c) {
            const float* wr = &w2s[c * 64 + k4 * 4];
            acc[c] += xv.x * wr[0] + xv.y * wr[1] + xv.z * wr[2] + xv.w * wr[3];
        }
    }
    float ss = 0.f, sd = 0.f;
    #pragma unroll
    for (int c = 0; c < 10; ++c) {
        h2[(size_t)n * 10 + c] = acc[c];
        ss += acc[c] * a_src[c];
        sd += acc[c] * a_dst[c];
    }
    s2s[n] = ss;
    s2d[n] = sd;
}

// ---------------- Conv2 aggregation (gather) + normalize + bias + pool ----------------
__global__ __launch_bounds__(256) void agg2_pool_kernel(
    const int* __restrict__ offs, const int* __restrict__ csr_src,
    const float* __restrict__ h2, const float* __restrict__ s2s,
    const float* __restrict__ s2d, const float* __restrict__ b2,
    const int* __restrict__ batch, float* __restrict__ pooled,
    float* __restrict__ cnt, int N)
{
    int n = blockIdx.x * 256 + threadIdx.x;
    bool active = n < N;
    float vals[10];
    int g = -1;
    if (active) {
        g = batch[n];
        float sdst = s2d[n];
        float s = s2s[n] + sdst;
        s = (s >= 0.f) ? s : 0.2f * s;
        float w = __expf(s);
        float den = w;
        float acc[10];
        {
            const float2* hp = (const float2*)&h2[(size_t)n * 10];
            #pragma unroll
            for (int q = 0; q < 5; ++q) {
                float2 v = hp[q];
                acc[q*2] = w * v.x; acc[q*2+1] = w * v.y;
            }
        }
        int row = offs[n], end = offs[n + 1];
        for (int i = row; i < end; ++i) {
            int src = csr_src[i];
            float ss = s2s[src] + sdst;
            ss = (ss >= 0.f) ? ss : 0.2f * ss;
            float we = __expf(ss);
            den += we;
            const float2* sp = (const float2*)&h2[(size_t)src * 10];
            #pragma unroll
            for (int q = 0; q < 5; ++q) {
                float2 v = sp[q];
                acc[q*2] += we * v.x; acc[q*2+1] += we * v.y;
            }
        }
        float inv = 1.f / (den + 1e-16f);
        #pragma unroll
        for (int c = 0; c < 10; ++c) vals[c] = acc[c] * inv + b2[c];
    } else {
        #pragma unroll
        for (int c = 0; c < 10; ++c) vals[c] = 0.f;
    }

    int lane = threadIdx.x & 63;
    int g0 = __shfl(g, 0);
    bool uniform = __all(g == g0 || g < 0);
    if (uniform) {
        if (g0 >= 0) {
            #pragma unroll
            for (int c = 0; c < 10; ++c) {
                float v = vals[c];
                for (int o = 32; o > 0; o >>= 1) v += __shfl_down(v, o);
                if (lane == 0) atomicAdd(&pooled[g0 * 10 + c], v);
            }
            float one = active ? 1.f : 0.f;
            for (int o = 32; o > 0; o >>= 1) one += __shfl_down(one, o);
            if (lane == 0) atomicAdd(&cnt[g0], one);
        }
    } else if (active) {
        #pragma unroll
        for (int c = 0; c < 10; ++c) atomicAdd(&pooled[g * 10 + c], vals[c]);
        atomicAdd(&cnt[g], 1.f);
    }
}

// ---------------- Final: mean + log_softmax ----------------
__global__ void final_kernel(const float* __restrict__ pooled,
                             const float* __restrict__ cnt, float* __restrict__ out)
{
    int g = threadIdx.x;
    if (g >= 64) return;
    float c = cnt[g];
    if (c < 1.f) c = 1.f;
    float v[10], m = -1e30f;
    #pragma unroll
    for (int i = 0; i < 10; ++i) {
        v[i] = pooled[g * 10 + i] / c;
        m = fmaxf(m, v[i]);
    }
    float s = 0.f;
    #pragma unroll
    for (int i = 0; i < 10; ++i) s += __expf(v[i] - m);
    float lse = m + logf(s);
    #pragma unroll
    for (int i = 0; i < 10; ++i) out[g * 10 + i] = v[i] - lse;
}

extern "C" void kernel_launch(void* const* d_in, const int* in_sizes, int n_in,
                              void* d_out, int out_size, void* d_ws, size_t ws_size,
                              hipStream_t stream) {
    const float* x       = (const float*)d_in[0];
    const int*   ei      = (const int*)  d_in[1];
    const int*   batch   = (const int*)  d_in[2];
    const float* W1      = (const float*)d_in[3];
    const float* a_src1  = (const float*)d_in[4];
    const float* a_dst1  = (const float*)d_in[5];
    const float* b1      = (const float*)d_in[6];
    const float* W2      = (const float*)d_in[7];
    const float* a_src2  = (const float*)d_in[8];
    const float* a_dst2  = (const float*)d_in[9];
    const float* b2      = (const float*)d_in[10];
    float* out = (float*)d_out;

    int N = in_sizes[0] / 128;
    int E = in_sizes[1] / 2;
    int NBK = (N + BWIDTH - 1) >> BSHIFT;

    float* f = (float*)d_ws;
    size_t off = 0;
    float* h1   = f + off;            // [N,64]; h2 aliases (h1 dead after agg1)
    float* h2   = h1;
    off += (size_t)N * 64;
    float* s1s  = f + off; float* s2s = s1s; off += (size_t)N * 4;
    float* s1d  = f + off; float* s2d = s1d; off += (size_t)N * 4;
    float* x2   = f + off;
    int*  pairs = (int*)x2;
    off += (size_t)N * 64;
    int* iw = (int*)(f + off);
    size_t ioff = 0;
    int* offs    = iw + ioff; ioff += (size_t)N + 1;
    int* csr_src = iw + ioff; ioff += (size_t)E;
    int* bb      = iw + ioff; ioff += (size_t)NBK + 1;
    int* bcur    = iw + ioff; ioff += (size_t)NBK;
    int*   bhist  = iw + ioff;
    float* pooled = (float*)(iw + ioff + NBK);
    float* cnt    = pooled + 640;

    hipMemsetAsync((void*)bhist, 0, ((size_t)NBK + 704) * sizeof(int), stream);

    int g1_blocks = (N + G1_TN - 1) / G1_TN;
    gemm1_kernel<<<g1_blocks, 256, 0, stream>>>(x, W1, a_src1, a_dst1, h1, s1s, s1d, N);

    bhist_kernel<<<256, 256, 0, stream>>>(ei, bhist, E, NBK);
    bscan_kernel<<<1, 1024, 0, stream>>>(bhist, bb, bcur, NBK);
    int ntiles = (E + A3_TILE - 1) / A3_TILE;
    partition_kernel<<<ntiles, 256, 0, stream>>>(ei, bcur, pairs, E, NBK);
    offs_kernel<<<NBK, 128, 0, stream>>>(pairs, bb, offs, N, NBK, E);
    scat_kernel<<<NBK, 128, 0, stream>>>(pairs, bb, offs, csr_src, N);

    agg1_kernel<<<(N * 4 + 255) / 256, 256, 0, stream>>>(
        offs, csr_src, h1, s1s, s1d, b1, x2, N);

    gemm2_kernel<<<(N + 255) / 256, 256, 0, stream>>>(x2, W2, a_src2, a_dst2, h2, s2s, s2d, N);

    agg2_pool_kernel<<<(N + 255) / 256, 256, 0, stream>>>(
        offs, csr_src, h2, s2s, s2d, b2, batch, pooled, cnt, N);

    final_kernel<<<1, 64, 0, stream>>>(pooled, cnt, out);
}

// Round 5
// 311.528 us; speedup vs baseline: 23.6954x; 1.0591x over previous
//
#include <hip/hip_runtime.h>
#include <hip/hip_bf16.h>
#include <math.h>

#define BSHIFT 7
#define BWIDTH (1 << BSHIFT)       // 128 dst per bucket
#define A3_TILE 2048

// ---------------- GEMM1: h1 = x @ W1^T, plus s_src1/s_dst1 ----------------
// register-tiled 8x8: block = 256 nodes x 64 ch, K-chunks of 16
#define G1_TN 256
#define G1_KC 16
__global__ __launch_bounds__(256) void gemm1_kernel(
    const float* __restrict__ x, const float* __restrict__ W1,
    const float* __restrict__ a_src, const float* __restrict__ a_dst,
    float* __restrict__ h1, float* __restrict__ s1s, float* __restrict__ s1d, int N)
{
    __shared__ float Ws[128 * 64];      // Ws[k*64+c] = W1[c*128+k]
    __shared__ float xs[G1_KC][260];    // xs[kk][node_local]
    int tid = threadIdx.x;
    int nb = blockIdx.x * G1_TN;

    for (int i = tid; i < 64 * 128; i += 256) {
        int k = i >> 6, c = i & 63;
        Ws[i] = W1[c * 128 + k];
    }

    int ng = tid & 31;
    int cg = tid >> 5;
    int c0 = cg * 8;
    float acc[8][8];
    #pragma unroll
    for (int q = 0; q < 8; ++q)
        #pragma unroll
        for (int j = 0; j < 8; ++j) acc[q][j] = 0.f;

    for (int kc = 0; kc < 128; kc += G1_KC) {
        __syncthreads();
        #pragma unroll
        for (int r = 0; r < 4; ++r) {
            int i4 = tid + r * 256;
            int nl = i4 >> 2;
            int kk4 = (i4 & 3) * 4;
            int n = nb + nl;
            float4 v = (n < N) ? *(const float4*)&x[(size_t)n * 128 + kc + kk4]
                               : make_float4(0.f, 0.f, 0.f, 0.f);
            xs[kk4 + 0][nl] = v.x;
            xs[kk4 + 1][nl] = v.y;
            xs[kk4 + 2][nl] = v.z;
            xs[kk4 + 3][nl] = v.w;
        }
        __syncthreads();
        #pragma unroll
        for (int kk = 0; kk < G1_KC; ++kk) {
            float4 xa = *(const float4*)&xs[kk][ng * 4];
            float4 xb = *(const float4*)&xs[kk][128 + ng * 4];
            const float* wr = &Ws[(kc + kk) * 64 + c0];
            float4 w0 = *(const float4*)&wr[0];
            float4 w1 = *(const float4*)&wr[4];
            float xv[8] = {xa.x, xa.y, xa.z, xa.w, xb.x, xb.y, xb.z, xb.w};
            float wv[8] = {w0.x, w0.y, w0.z, w0.w, w1.x, w1.y, w1.z, w1.w};
            #pragma unroll
            for (int q = 0; q < 8; ++q)
                #pragma unroll
                for (int j = 0; j < 8; ++j)
                    acc[q][j] += xv[q] * wv[j];
        }
    }

    #pragma unroll
    for (int q = 0; q < 8; ++q) {
        int nl = (q < 4) ? (ng * 4 + q) : (128 + ng * 4 + (q - 4));
        int n = nb + nl;
        float ss = 0.f, sd = 0.f;
        #pragma unroll
        for (int j = 0; j < 8; ++j) {
            ss += acc[q][j] * a_src[c0 + j];
            sd += acc[q][j] * a_dst[c0 + j];
        }
        ss += __shfl_xor(ss, 32);
        sd += __shfl_xor(sd, 32);
        if (n < N) {
            *(float4*)&h1[(size_t)n * 64 + c0] =
                make_float4(acc[q][0], acc[q][1], acc[q][2], acc[q][3]);
            *(float4*)&h1[(size_t)n * 64 + c0 + 4] =
                make_float4(acc[q][4], acc[q][5], acc[q][6], acc[q][7]);
            if ((cg & 1) == 0) {
                s1s[n * 4 + (cg >> 1)] = ss;
                s1d[n * 4 + (cg >> 1)] = sd;
            }
        }
    }
}

// ---------------- A1: bucket histogram (LDS-staged) ----------------
__global__ __launch_bounds__(256) void bhist_kernel(
    const int* __restrict__ ei, int* __restrict__ bhist, int E, int NBK)
{
    __shared__ int h[1024];
    for (int i = threadIdx.x; i < 1024; i += 256) h[i] = 0;
    __syncthreads();
    int stride = gridDim.x * 256;
    for (int e = blockIdx.x * 256 + threadIdx.x; e < E; e += stride)
        atomicAdd(&h[ei[E + e] >> BSHIFT], 1);
    __syncthreads();
    for (int b = threadIdx.x; b < NBK; b += 256) {
        int c = h[b];
        if (c) atomicAdd(&bhist[b], c);
    }
}

// ---------------- A2: exclusive scan over buckets -> bb, bcur ----------------
__global__ __launch_bounds__(1024) void bscan_kernel(
    const int* __restrict__ bhist, int* __restrict__ bb, int* __restrict__ bcur, int NBK)
{
    __shared__ int sh[1024];
    int t = threadIdx.x;
    int v = (t < NBK) ? bhist[t] : 0;
    sh[t] = v;
    __syncthreads();
    for (int o = 1; o < 1024; o <<= 1) {
        int u = (t >= o) ? sh[t - o] : 0;
        __syncthreads();
        sh[t] += u;
        __syncthreads();
    }
    int incl = sh[t];
    int excl = incl - v;
    if (t < NBK) { bb[t] = excl; bcur[t] = excl; }
    if (t == NBK - 1) bb[NBK] = incl;
}

// ---------------- A3: partition edges into bucket regions (packed) ----------------
__global__ __launch_bounds__(256) void partition_kernel(
    const int* __restrict__ ei, int* __restrict__ bcur, int* __restrict__ pairs,
    int E, int NBK)
{
    __shared__ int hist[1024];
    __shared__ int scanb[1024];
    __shared__ int gbase[1024];
    __shared__ int partial[256];
    __shared__ int stage_pack[A3_TILE];
    __shared__ int stage_pos[A3_TILE];
    int t = threadIdx.x;
    int e0 = blockIdx.x * A3_TILE;
    for (int i = t; i < 1024; i += 256) hist[i] = 0;
    __syncthreads();
    int my_b[8], my_rank[8], my_pack[8];
    #pragma unroll
    for (int j = 0; j < 8; ++j) {
        int e = e0 + j * 256 + t;
        int b = -1, pack = 0, r = 0;
        if (e < E) {
            int s = ei[e], d = ei[E + e];
            b = d >> BSHIFT;
            pack = ((d & (BWIDTH - 1)) << 17) | s;
            r = atomicAdd(&hist[b], 1);
        }
        my_b[j] = b; my_pack[j] = pack; my_rank[j] = r;
    }
    __syncthreads();
    int b4 = t * 4;
    int h0 = hist[b4], h1v = hist[b4 + 1], h2v = hist[b4 + 2], h3v = hist[b4 + 3];
    int tot = h0 + h1v + h2v + h3v;
    partial[t] = tot;
    __syncthreads();
    for (int o = 1; o < 256; o <<= 1) {
        int u = (t >= o) ? partial[t - o] : 0;
        __syncthreads();
        partial[t] += u;
        __syncthreads();
    }
    int excl = partial[t] - tot;
    scanb[b4]     = excl;
    scanb[b4 + 1] = excl + h0;
    scanb[b4 + 2] = excl + h0 + h1v;
    scanb[b4 + 3] = excl + h0 + h1v + h2v;
    int nvalid = partial[255];
    for (int b = t; b < NBK; b += 256) {
        int c = hist[b];
        if (c > 0) gbase[b] = atomicAdd(&bcur[b], c);
    }
    __syncthreads();
    #pragma unroll
    for (int j = 0; j < 8; ++j) {
        int b = my_b[j];
        if (b >= 0) {
            int slot = scanb[b] + my_rank[j];
            stage_pack[slot] = my_pack[j];
            stage_pos[slot]  = gbase[b] + my_rank[j];
        }
    }
    __syncthreads();
    for (int i = t; i < nvalid; i += 256)
        pairs[stage_pos[i]] = stage_pack[i];
}

// ---------------- B1: per-dst offs directly from bucket ----------------
__global__ __launch_bounds__(128) void offs_kernel(
    const int* __restrict__ pairs, const int* __restrict__ bb,
    int* __restrict__ offs, int N, int NBK, int E)
{
    int b = blockIdx.x;
    __shared__ int hist[BWIDTH];
    int t = threadIdx.x;
    hist[t] = 0;
    __syncthreads();
    int s = bb[b], e = bb[b + 1];
    for (int i = s + t; i < e; i += 128)
        atomicAdd(&hist[(pairs[i] >> 17) & (BWIDTH - 1)], 1);
    __syncthreads();
    int v = hist[t];
    for (int o = 1; o < BWIDTH; o <<= 1) {
        int u = (t >= o) ? hist[t - o] : 0;
        __syncthreads();
        hist[t] += u;
        __syncthreads();
    }
    int excl = hist[t] - v;
    int dst = b * BWIDTH + t;
    if (dst < N) offs[dst] = s + excl;
    if (b == 0 && t == 0) offs[N] = E;
}

// ---------------- B2: scatter src into CSR, LDS cursors ----------------
__global__ __launch_bounds__(128) void scat_kernel(
    const int* __restrict__ pairs, const int* __restrict__ bb,
    const int* __restrict__ offs, int* __restrict__ csr_src, int N)
{
    int b = blockIdx.x;
    __shared__ int cur[BWIDTH];
    int t = threadIdx.x;
    int dst = b * BWIDTH + t;
    cur[t] = (dst < N) ? offs[dst] : 0;
    __syncthreads();
    int s = bb[b], e = bb[b + 1];
    for (int i = s + t; i < e; i += 128) {
        int p = pairs[i];
        int pos = atomicAdd(&cur[(p >> 17) & (BWIDTH - 1)], 1);
        csr_src[pos] = p & 0x1FFFF;
    }
}

// ---- Conv1 aggregation + ELU + FUSED gemm2 + layer-2 scores -> h2p[N,16] ----
// 4 threads (heads) per node; h2p row = [c0..c9, ss2, sd2, x, x, x, x]
__global__ __launch_bounds__(256) void agg1_kernel(
    const int* __restrict__ offs, const int* __restrict__ csr_src,
    const float* __restrict__ h1, const float* __restrict__ s1s,
    const float* __restrict__ s1d, const float* __restrict__ b1,
    const float* __restrict__ W2, const float* __restrict__ as2,
    const float* __restrict__ ad2, float* __restrict__ h2p, int N)
{
    __shared__ float w2s[640];
    for (int i = threadIdx.x; i < 640; i += 256) w2s[i] = W2[i];
    __syncthreads();

    int tid = blockIdx.x * 256 + threadIdx.x;
    int n = tid >> 2, h = tid & 3;
    float xl[16];
    #pragma unroll
    for (int j = 0; j < 16; ++j) xl[j] = 0.f;

    if (n < N) {
        float sdst = s1d[n * 4 + h];
        float s = s1s[n * 4 + h] + sdst;
        s = (s >= 0.f) ? s : 0.2f * s;
        float w = __expf(s);
        float den = w;
        {
            const float4* hp = (const float4*)&h1[(size_t)n * 64 + h * 16];
            #pragma unroll
            for (int q = 0; q < 4; ++q) {
                float4 v = hp[q];
                xl[q*4+0] = w * v.x; xl[q*4+1] = w * v.y;
                xl[q*4+2] = w * v.z; xl[q*4+3] = w * v.w;
            }
        }
        int row = offs[n], end = offs[n + 1];
        for (int i = row; i < end; ++i) {
            int src = csr_src[i];
            float ss = s1s[src * 4 + h] + sdst;
            ss = (ss >= 0.f) ? ss : 0.2f * ss;
            float we = __expf(ss);
            den += we;
            const float4* sp = (const float4*)&h1[(size_t)src * 64 + h * 16];
            #pragma unroll
            for (int q = 0; q < 4; ++q) {
                float4 v = sp[q];
                xl[q*4+0] += we * v.x; xl[q*4+1] += we * v.y;
                xl[q*4+2] += we * v.z; xl[q*4+3] += we * v.w;
            }
        }
        float inv = 1.f / (den + 1e-16f);
        #pragma unroll
        for (int j = 0; j < 16; ++j) {
            float v = xl[j] * inv + b1[h * 16 + j];
            xl[j] = (v > 0.f) ? v : (__expf(v) - 1.f);
        }
    }

    // fused layer-2 matmul: part[c] = sum_j xl[j] * W2[c][h*16+j]
    float part[10];
    #pragma unroll
    for (int c = 0; c < 10; ++c) {
        const float* wr = &w2s[c * 64 + h * 16];
        float p = 0.f;
        #pragma unroll
        for (int j = 0; j < 16; ++j) p += xl[j] * wr[j];
        part[c] = p;
    }
    #pragma unroll
    for (int c = 0; c < 10; ++c) {
        part[c] += __shfl_xor(part[c], 1);
        part[c] += __shfl_xor(part[c], 2);
    }
    if (n < N) {
        if (h == 0)
            *(float4*)&h2p[(size_t)n * 16] =
                make_float4(part[0], part[1], part[2], part[3]);
        else if (h == 1)
            *(float4*)&h2p[(size_t)n * 16 + 4] =
                make_float4(part[4], part[5], part[6], part[7]);
        else if (h == 2) {
            float ss = 0.f, sd = 0.f;
            #pragma unroll
            for (int c = 0; c < 10; ++c) {
                ss += part[c] * as2[c];
                sd += part[c] * ad2[c];
            }
            *(float4*)&h2p[(size_t)n * 16 + 8] =
                make_float4(part[8], part[9], ss, sd);
        }
    }
}

// ---- Conv2 aggregation (4 threads/node, padded rows) + normalize + pool ----
__global__ __launch_bounds__(256) void agg2_pool_kernel(
    const int* __restrict__ offs, const int* __restrict__ csr_src,
    const float* __restrict__ h2p, const float* __restrict__ b2,
    const int* __restrict__ batch, float* __restrict__ pooled,
    float* __restrict__ cnt, int N)
{
    int tid = blockIdx.x * 256 + threadIdx.x;
    int n = tid >> 2, t = tid & 3;
    bool active = n < N;
    float acc[10];
    #pragma unroll
    for (int c = 0; c < 10; ++c) acc[c] = 0.f;
    float den = 0.f;
    int g = -1;
    if (active) {
        g = batch[n];
        const float4* dr = (const float4*)&h2p[(size_t)n * 16];
        float4 d2 = dr[2];               // {c8, c9, ss, sd}
        float sdst = d2.w;
        if (t == 0) {
            float4 d0 = dr[0], d1 = dr[1];
            float s = d2.z + sdst;
            s = (s >= 0.f) ? s : 0.2f * s;
            float w = __expf(s);
            den = w;
            acc[0] = w*d0.x; acc[1] = w*d0.y; acc[2] = w*d0.z; acc[3] = w*d0.w;
            acc[4] = w*d1.x; acc[5] = w*d1.y; acc[6] = w*d1.z; acc[7] = w*d1.w;
            acc[8] = w*d2.x; acc[9] = w*d2.y;
        }
        int row = offs[n], end = offs[n + 1];
        for (int i = row + t; i < end; i += 4) {
            int src = csr_src[i];
            const float4* sr = (const float4*)&h2p[(size_t)src * 16];
            float4 s0 = sr[0], s1 = sr[1], s2 = sr[2];
            float s = s2.z + sdst;
            s = (s >= 0.f) ? s : 0.2f * s;
            float we = __expf(s);
            den += we;
            acc[0] += we*s0.x; acc[1] += we*s0.y; acc[2] += we*s0.z; acc[3] += we*s0.w;
            acc[4] += we*s1.x; acc[5] += we*s1.y; acc[6] += we*s1.z; acc[7] += we*s1.w;
            acc[8] += we*s2.x; acc[9] += we*s2.y;
        }
    }
    // quad butterfly: all 4 lanes of the node get full sums
    #pragma unroll
    for (int c = 0; c < 10; ++c) {
        acc[c] += __shfl_xor(acc[c], 1);
        acc[c] += __shfl_xor(acc[c], 2);
    }
    den += __shfl_xor(den, 1);
    den += __shfl_xor(den, 2);

    bool leader = active && (t == 0);
    float inv = 1.f / (den + 1e-16f);
    float vals[10];
    #pragma unroll
    for (int c = 0; c < 10; ++c)
        vals[c] = leader ? (acc[c] * inv + b2[c]) : 0.f;

    int lane = threadIdx.x & 63;
    int g0 = __shfl(g, 0);
    bool uniform = __all(g == g0 || g < 0);
    if (uniform) {
        if (g0 >= 0) {
            #pragma unroll
            for (int c = 0; c < 10; ++c) {
                float v = vals[c];
                for (int o = 32; o > 0; o >>= 1) v += __shfl_down(v, o);
                if (lane == 0) atomicAdd(&pooled[g0 * 10 + c], v);
            }
            float one = leader ? 1.f : 0.f;
            for (int o = 32; o > 0; o >>= 1) one += __shfl_down(one, o);
            if (lane == 0) atomicAdd(&cnt[g0], one);
        }
    } else if (leader) {
        #pragma unroll
        for (int c = 0; c < 10; ++c) atomicAdd(&pooled[g * 10 + c], vals[c]);
        atomicAdd(&cnt[g], 1.f);
    }
}

// ---------------- Final: mean + log_softmax ----------------
__global__ void final_kernel(const float* __restrict__ pooled,
                             const float* __restrict__ cnt, float* __restrict__ out)
{
    int g = threadIdx.x;
    if (g >= 64) return;
    float c = cnt[g];
    if (c < 1.f) c = 1.f;
    float v[10], m = -1e30f;
    #pragma unroll
    for (int i = 0; i < 10; ++i) {
        v[i] = pooled[g * 10 + i] / c;
        m = fmaxf(m, v[i]);
    }
    float s = 0.f;
    #pragma unroll
    for (int i = 0; i < 10; ++i) s += __expf(v[i] - m);
    float lse = m + logf(s);
    #pragma unroll
    for (int i = 0; i < 10; ++i) out[g * 10 + i] = v[i] - lse;
}

extern "C" void kernel_launch(void* const* d_in, const int* in_sizes, int n_in,
                              void* d_out, int out_size, void* d_ws, size_t ws_size,
                              hipStream_t stream) {
    const float* x       = (const float*)d_in[0];
    const int*   ei      = (const int*)  d_in[1];
    const int*   batch   = (const int*)  d_in[2];
    const float* W1      = (const float*)d_in[3];
    const float* a_src1  = (const float*)d_in[4];
    const float* a_dst1  = (const float*)d_in[5];
    const float* b1      = (const float*)d_in[6];
    const float* W2      = (const float*)d_in[7];
    const float* a_src2  = (const float*)d_in[8];
    const float* a_dst2  = (const float*)d_in[9];
    const float* b2      = (const float*)d_in[10];
    float* out = (float*)d_out;

    int N = in_sizes[0] / 128;
    int E = in_sizes[1] / 2;
    int NBK = (N + BWIDTH - 1) >> BSHIFT;

    float* f = (float*)d_ws;
    size_t off = 0;
    float* h1   = f + off; off += (size_t)N * 64;
    float* s1s  = f + off; off += (size_t)N * 4;
    float* s1d  = f + off; off += (size_t)N * 4;
    // time-aliased region: pairs (E ints, live A3..scat) then h2p (N*16 floats, agg1..agg2)
    float* h2p  = f + off;
    int*  pairs = (int*)h2p;
    size_t r1 = (size_t)N * 16 > (size_t)E ? (size_t)N * 16 : (size_t)E;
    off += r1;
    int* iw = (int*)(f + off);
    size_t ioff = 0;
    int* offs    = iw + ioff; ioff += (size_t)N + 1;
    int* csr_src = iw + ioff; ioff += (size_t)E;
    int* bb      = iw + ioff; ioff += (size_t)NBK + 1;
    int* bcur    = iw + ioff; ioff += (size_t)NBK;
    int*   bhist  = iw + ioff;
    float* pooled = (float*)(iw + ioff + NBK);
    float* cnt    = pooled + 640;

    hipMemsetAsync((void*)bhist, 0, ((size_t)NBK + 704) * sizeof(int), stream);

    int g1_blocks = (N + G1_TN - 1) / G1_TN;
    gemm1_kernel<<<g1_blocks, 256, 0, stream>>>(x, W1, a_src1, a_dst1, h1, s1s, s1d, N);

    bhist_kernel<<<256, 256, 0, stream>>>(ei, bhist, E, NBK);
    bscan_kernel<<<1, 1024, 0, stream>>>(bhist, bb, bcur, NBK);
    int ntiles = (E + A3_TILE - 1) / A3_TILE;
    partition_kernel<<<ntiles, 256, 0, stream>>>(ei, bcur, pairs, E, NBK);
    offs_kernel<<<NBK, 128, 0, stream>>>(pairs, bb, offs, N, NBK, E);
    scat_kernel<<<NBK, 128, 0, stream>>>(pairs, bb, offs, csr_src, N);

    agg1_kernel<<<(N * 4 + 255) / 256, 256, 0, stream>>>(
        offs, csr_src, h1, s1s, s1d, b1, W2, a_src2, a_dst2, h2p, N);

    agg2_pool_kernel<<<(N * 4 + 255) / 256, 256, 0, stream>>>(
        offs, csr_src, h2p, b2, batch, pooled, cnt, N);

    final_kernel<<<1, 64, 0, stream>>>(pooled, cnt, out);
}

// Round 6
// 262.308 us; speedup vs baseline: 28.1417x; 1.1876x over previous
//
#include <hip/hip_runtime.h>
#include <hip/hip_bf16.h>
#include <math.h>

#define BSHIFT 7
#define BWIDTH (1 << BSHIFT)       // 128 dst per bucket
#define A3_TILE 2048

__device__ inline unsigned int f2bf(float f) {
    unsigned int u = __float_as_uint(f);
    return (u + 0x7FFFu + ((u >> 16) & 1u)) >> 16;   // RNE
}
__device__ inline float bflo(unsigned int u) { return __uint_as_float(u << 16); }
__device__ inline float bfhi(unsigned int u) { return __uint_as_float(u & 0xFFFF0000u); }

// ---------------- GEMM1: h1b(bf16) = x @ W1^T, plus s_src1/s_dst1 ----------------
#define G1_TN 256
#define G1_KC 16
__global__ __launch_bounds__(256) void gemm1_kernel(
    const float* __restrict__ x, const float* __restrict__ W1,
    const float* __restrict__ a_src, const float* __restrict__ a_dst,
    unsigned short* __restrict__ h1b, float* __restrict__ s1s,
    float* __restrict__ s1d, int N)
{
    __shared__ float Ws[128 * 64];      // Ws[k*64+c] = W1[c*128+k]
    __shared__ float xs[G1_KC][260];
    int tid = threadIdx.x;
    int nb = blockIdx.x * G1_TN;

    for (int i = tid; i < 64 * 128; i += 256) {
        int k = i >> 6, c = i & 63;
        Ws[i] = W1[c * 128 + k];
    }

    int ng = tid & 31;
    int cg = tid >> 5;
    int c0 = cg * 8;
    float acc[8][8];
    #pragma unroll
    for (int q = 0; q < 8; ++q)
        #pragma unroll
        for (int j = 0; j < 8; ++j) acc[q][j] = 0.f;

    for (int kc = 0; kc < 128; kc += G1_KC) {
        __syncthreads();
        #pragma unroll
        for (int r = 0; r < 4; ++r) {
            int i4 = tid + r * 256;
            int nl = i4 >> 2;
            int kk4 = (i4 & 3) * 4;
            int n = nb + nl;
            float4 v = (n < N) ? *(const float4*)&x[(size_t)n * 128 + kc + kk4]
                               : make_float4(0.f, 0.f, 0.f, 0.f);
            xs[kk4 + 0][nl] = v.x;
            xs[kk4 + 1][nl] = v.y;
            xs[kk4 + 2][nl] = v.z;
            xs[kk4 + 3][nl] = v.w;
        }
        __syncthreads();
        #pragma unroll
        for (int kk = 0; kk < G1_KC; ++kk) {
            float4 xa = *(const float4*)&xs[kk][ng * 4];
            float4 xb = *(const float4*)&xs[kk][128 + ng * 4];
            const float* wr = &Ws[(kc + kk) * 64 + c0];
            float4 w0 = *(const float4*)&wr[0];
            float4 w1 = *(const float4*)&wr[4];
            float xv[8] = {xa.x, xa.y, xa.z, xa.w, xb.x, xb.y, xb.z, xb.w};
            float wv[8] = {w0.x, w0.y, w0.z, w0.w, w1.x, w1.y, w1.z, w1.w};
            #pragma unroll
            for (int q = 0; q < 8; ++q)
                #pragma unroll
                for (int j = 0; j < 8; ++j)
                    acc[q][j] += xv[q] * wv[j];
        }
    }

    #pragma unroll
    for (int q = 0; q < 8; ++q) {
        int nl = (q < 4) ? (ng * 4 + q) : (128 + ng * 4 + (q - 4));
        int n = nb + nl;
        float ss = 0.f, sd = 0.f;
        #pragma unroll
        for (int j = 0; j < 8; ++j) {
            ss += acc[q][j] * a_src[c0 + j];
            sd += acc[q][j] * a_dst[c0 + j];
        }
        ss += __shfl_xor(ss, 32);
        sd += __shfl_xor(sd, 32);
        if (n < N) {
            uint4 pk;
            pk.x = f2bf(acc[q][0]) | (f2bf(acc[q][1]) << 16);
            pk.y = f2bf(acc[q][2]) | (f2bf(acc[q][3]) << 16);
            pk.z = f2bf(acc[q][4]) | (f2bf(acc[q][5]) << 16);
            pk.w = f2bf(acc[q][6]) | (f2bf(acc[q][7]) << 16);
            *(uint4*)(h1b + (size_t)n * 64 + c0) = pk;
            if ((cg & 1) == 0) {
                s1s[n * 4 + (cg >> 1)] = ss;
                s1d[n * 4 + (cg >> 1)] = sd;
            }
        }
    }
}

// ---------------- A1: bucket histogram (LDS-staged) ----------------
__global__ __launch_bounds__(256) void bhist_kernel(
    const int* __restrict__ ei, int* __restrict__ bhist, int E, int NBK)
{
    __shared__ int h[1024];
    for (int i = threadIdx.x; i < 1024; i += 256) h[i] = 0;
    __syncthreads();
    int stride = gridDim.x * 256;
    for (int e = blockIdx.x * 256 + threadIdx.x; e < E; e += stride)
        atomicAdd(&h[ei[E + e] >> BSHIFT], 1);
    __syncthreads();
    for (int b = threadIdx.x; b < NBK; b += 256) {
        int c = h[b];
        if (c) atomicAdd(&bhist[b], c);
    }
}

// ---------------- A2: exclusive scan over buckets -> bb, bcur ----------------
__global__ __launch_bounds__(1024) void bscan_kernel(
    const int* __restrict__ bhist, int* __restrict__ bb, int* __restrict__ bcur, int NBK)
{
    __shared__ int sh[1024];
    int t = threadIdx.x;
    int v = (t < NBK) ? bhist[t] : 0;
    sh[t] = v;
    __syncthreads();
    for (int o = 1; o < 1024; o <<= 1) {
        int u = (t >= o) ? sh[t - o] : 0;
        __syncthreads();
        sh[t] += u;
        __syncthreads();
    }
    int incl = sh[t];
    int excl = incl - v;
    if (t < NBK) { bb[t] = excl; bcur[t] = excl; }
    if (t == NBK - 1) bb[NBK] = incl;
}

// ---------------- A3: partition edges into bucket regions (packed) ----------------
__global__ __launch_bounds__(256) void partition_kernel(
    const int* __restrict__ ei, int* __restrict__ bcur, int* __restrict__ pairs,
    int E, int NBK)
{
    __shared__ int hist[1024];
    __shared__ int scanb[1024];
    __shared__ int gbase[1024];
    __shared__ int partial[256];
    __shared__ int stage_pack[A3_TILE];
    __shared__ int stage_pos[A3_TILE];
    int t = threadIdx.x;
    int e0 = blockIdx.x * A3_TILE;
    for (int i = t; i < 1024; i += 256) hist[i] = 0;
    __syncthreads();
    int my_b[8], my_rank[8], my_pack[8];
    #pragma unroll
    for (int j = 0; j < 8; ++j) {
        int e = e0 + j * 256 + t;
        int b = -1, pack = 0, r = 0;
        if (e < E) {
            int s = ei[e], d = ei[E + e];
            b = d >> BSHIFT;
            pack = ((d & (BWIDTH - 1)) << 17) | s;
            r = atomicAdd(&hist[b], 1);
        }
        my_b[j] = b; my_pack[j] = pack; my_rank[j] = r;
    }
    __syncthreads();
    int b4 = t * 4;
    int h0 = hist[b4], h1v = hist[b4 + 1], h2v = hist[b4 + 2], h3v = hist[b4 + 3];
    int tot = h0 + h1v + h2v + h3v;
    partial[t] = tot;
    __syncthreads();
    for (int o = 1; o < 256; o <<= 1) {
        int u = (t >= o) ? partial[t - o] : 0;
        __syncthreads();
        partial[t] += u;
        __syncthreads();
    }
    int excl = partial[t] - tot;
    scanb[b4]     = excl;
    scanb[b4 + 1] = excl + h0;
    scanb[b4 + 2] = excl + h0 + h1v;
    scanb[b4 + 3] = excl + h0 + h1v + h2v;
    int nvalid = partial[255];
    for (int b = t; b < NBK; b += 256) {
        int c = hist[b];
        if (c > 0) gbase[b] = atomicAdd(&bcur[b], c);
    }
    __syncthreads();
    #pragma unroll
    for (int j = 0; j < 8; ++j) {
        int b = my_b[j];
        if (b >= 0) {
            int slot = scanb[b] + my_rank[j];
            stage_pack[slot] = my_pack[j];
            stage_pos[slot]  = gbase[b] + my_rank[j];
        }
    }
    __syncthreads();
    for (int i = t; i < nvalid; i += 256)
        pairs[stage_pos[i]] = stage_pack[i];
}

// ---------------- B1: per-dst offs directly from bucket ----------------
__global__ __launch_bounds__(128) void offs_kernel(
    const int* __restrict__ pairs, const int* __restrict__ bb,
    int* __restrict__ offs, int N, int NBK, int E)
{
    int b = blockIdx.x;
    __shared__ int hist[BWIDTH];
    int t = threadIdx.x;
    hist[t] = 0;
    __syncthreads();
    int s = bb[b], e = bb[b + 1];
    for (int i = s + t; i < e; i += 128)
        atomicAdd(&hist[(pairs[i] >> 17) & (BWIDTH - 1)], 1);
    __syncthreads();
    int v = hist[t];
    for (int o = 1; o < BWIDTH; o <<= 1) {
        int u = (t >= o) ? hist[t - o] : 0;
        __syncthreads();
        hist[t] += u;
        __syncthreads();
    }
    int excl = hist[t] - v;
    int dst = b * BWIDTH + t;
    if (dst < N) offs[dst] = s + excl;
    if (b == 0 && t == 0) offs[N] = E;
}

// ---------------- B2: scatter src into CSR, LDS cursors ----------------
__global__ __launch_bounds__(128) void scat_kernel(
    const int* __restrict__ pairs, const int* __restrict__ bb,
    const int* __restrict__ offs, int* __restrict__ csr_src, int N)
{
    int b = blockIdx.x;
    __shared__ int cur[BWIDTH];
    int t = threadIdx.x;
    int dst = b * BWIDTH + t;
    cur[t] = (dst < N) ? offs[dst] : 0;
    __syncthreads();
    int s = bb[b], e = bb[b + 1];
    for (int i = s + t; i < e; i += 128) {
        int p = pairs[i];
        int pos = atomicAdd(&cur[(p >> 17) & (BWIDTH - 1)], 1);
        csr_src[pos] = p & 0x1FFFF;
    }
}

// ---- Conv1 aggregation (bf16 gather) + ELU + FUSED gemm2 -> h2p[N,16] bf16 ----
// 8 threads per node: 4 heads x 2 edge-halves; h2p row = [c0..c9, ss2, sd2, pad]
__global__ __launch_bounds__(256) void agg1_kernel(
    const int* __restrict__ offs, const int* __restrict__ csr_src,
    const unsigned short* __restrict__ h1b, const float* __restrict__ s1s,
    const float* __restrict__ s1d, const float* __restrict__ b1,
    const float* __restrict__ W2, const float* __restrict__ as2,
    const float* __restrict__ ad2, unsigned short* __restrict__ h2p, int N)
{
    __shared__ float w2s[640];
    for (int i = threadIdx.x; i < 640; i += 256) w2s[i] = W2[i];
    __syncthreads();

    int tid = blockIdx.x * 256 + threadIdx.x;
    int n = tid >> 3, h = tid & 3, half = (tid >> 2) & 1;
    float xl[16];
    #pragma unroll
    for (int j = 0; j < 16; ++j) xl[j] = 0.f;
    float den = 0.f;

    if (n < N) {
        float sdst = s1d[n * 4 + h];
        if (half == 0) {   // self-loop
            float s = s1s[n * 4 + h] + sdst;
            s = (s >= 0.f) ? s : 0.2f * s;
            float w = __expf(s);
            den = w;
            const uint4* hp = (const uint4*)(h1b + ((size_t)n << 6) + (h << 4));
            uint4 a = hp[0], b = hp[1];
            xl[0] = w * bflo(a.x); xl[1] = w * bfhi(a.x);
            xl[2] = w * bflo(a.y); xl[3] = w * bfhi(a.y);
            xl[4] = w * bflo(a.z); xl[5] = w * bfhi(a.z);
            xl[6] = w * bflo(a.w); xl[7] = w * bfhi(a.w);
            xl[8]  = w * bflo(b.x); xl[9]  = w * bfhi(b.x);
            xl[10] = w * bflo(b.y); xl[11] = w * bfhi(b.y);
            xl[12] = w * bflo(b.z); xl[13] = w * bfhi(b.z);
            xl[14] = w * bflo(b.w); xl[15] = w * bfhi(b.w);
        }
        int row = offs[n], end = offs[n + 1];
        for (int i = row + half; i < end; i += 2) {
            int src = csr_src[i];
            float ss = s1s[src * 4 + h] + sdst;
            ss = (ss >= 0.f) ? ss : 0.2f * ss;
            float we = __expf(ss);
            den += we;
            const uint4* sp = (const uint4*)(h1b + ((size_t)src << 6) + (h << 4));
            uint4 a = sp[0], b = sp[1];
            xl[0] += we * bflo(a.x); xl[1] += we * bfhi(a.x);
            xl[2] += we * bflo(a.y); xl[3] += we * bfhi(a.y);
            xl[4] += we * bflo(a.z); xl[5] += we * bfhi(a.z);
            xl[6] += we * bflo(a.w); xl[7] += we * bfhi(a.w);
            xl[8]  += we * bflo(b.x); xl[9]  += we * bfhi(b.x);
            xl[10] += we * bflo(b.y); xl[11] += we * bfhi(b.y);
            xl[12] += we * bflo(b.z); xl[13] += we * bfhi(b.z);
            xl[14] += we * bflo(b.w); xl[15] += we * bfhi(b.w);
        }
    }
    // merge edge-halves within each head
    #pragma unroll
    for (int j = 0; j < 16; ++j) xl[j] += __shfl_xor(xl[j], 4);
    den += __shfl_xor(den, 4);

    float inv = 1.f / (den + 1e-16f);
    #pragma unroll
    for (int j = 0; j < 16; ++j) {
        float v = xl[j] * inv + b1[h * 16 + j];
        xl[j] = (v > 0.f) ? v : (__expf(v) - 1.f);
    }

    // fused layer-2 matmul: part[c] = sum_j xl[j] * W2[c][h*16+j]
    float part[10];
    #pragma unroll
    for (int c = 0; c < 10; ++c) {
        const float* wr = &w2s[c * 64 + h * 16];
        float p = 0.f;
        #pragma unroll
        for (int j = 0; j < 16; ++j) p += xl[j] * wr[j];
        part[c] = p;
    }
    #pragma unroll
    for (int c = 0; c < 10; ++c) {
        part[c] += __shfl_xor(part[c], 1);
        part[c] += __shfl_xor(part[c], 2);
    }
    if (n < N && half == 0) {
        if (h == 0) {
            uint4 pk;
            pk.x = f2bf(part[0]) | (f2bf(part[1]) << 16);
            pk.y = f2bf(part[2]) | (f2bf(part[3]) << 16);
            pk.z = f2bf(part[4]) | (f2bf(part[5]) << 16);
            pk.w = f2bf(part[6]) | (f2bf(part[7]) << 16);
            *(uint4*)(h2p + (size_t)n * 16) = pk;
        } else if (h == 1) {
            float ss = 0.f, sd = 0.f;
            #pragma unroll
            for (int c = 0; c < 10; ++c) {
                ss += part[c] * as2[c];
                sd += part[c] * ad2[c];
            }
            uint2 pk;
            pk.x = f2bf(part[8]) | (f2bf(part[9]) << 16);
            pk.y = f2bf(ss) | (f2bf(sd) << 16);
            *(uint2*)(h2p + (size_t)n * 16 + 8) = pk;
        }
    }
}

// ---- Conv2 aggregation (bf16 rows, 4 threads/node) + normalize + pool ----
__global__ __launch_bounds__(256) void agg2_pool_kernel(
    const int* __restrict__ offs, const int* __restrict__ csr_src,
    const unsigned short* __restrict__ h2p, const float* __restrict__ b2,
    const int* __restrict__ batch, float* __restrict__ pooled,
    float* __restrict__ cnt, int N)
{
    int tid = blockIdx.x * 256 + threadIdx.x;
    int n = tid >> 2, t = tid & 3;
    bool active = n < N;
    float acc[10];
    #pragma unroll
    for (int c = 0; c < 10; ++c) acc[c] = 0.f;
    float den = 0.f;
    int g = -1;
    if (active) {
        g = batch[n];
        uint2 d1 = *(const uint2*)(h2p + (size_t)n * 16 + 8);  // {c8|c9, ss|sd}
        float sdst = bfhi(d1.y);
        if (t == 0) {
            uint4 d0 = *(const uint4*)(h2p + (size_t)n * 16);
            float s = bflo(d1.y) + sdst;
            s = (s >= 0.f) ? s : 0.2f * s;
            float w = __expf(s);
            den = w;
            acc[0] = w * bflo(d0.x); acc[1] = w * bfhi(d0.x);
            acc[2] = w * bflo(d0.y); acc[3] = w * bfhi(d0.y);
            acc[4] = w * bflo(d0.z); acc[5] = w * bfhi(d0.z);
            acc[6] = w * bflo(d0.w); acc[7] = w * bfhi(d0.w);
            acc[8] = w * bflo(d1.x); acc[9] = w * bfhi(d1.x);
        }
        int row = offs[n], end = offs[n + 1];
        for (int i = row + t; i < end; i += 4) {
            int src = csr_src[i];
            uint4 s0 = *(const uint4*)(h2p + (size_t)src * 16);
            uint2 s1 = *(const uint2*)(h2p + (size_t)src * 16 + 8);
            float s = bflo(s1.y) + sdst;
            s = (s >= 0.f) ? s : 0.2f * s;
            float we = __expf(s);
            den += we;
            acc[0] += we * bflo(s0.x); acc[1] += we * bfhi(s0.x);
            acc[2] += we * bflo(s0.y); acc[3] += we * bfhi(s0.y);
            acc[4] += we * bflo(s0.z); acc[5] += we * bfhi(s0.z);
            acc[6] += we * bflo(s0.w); acc[7] += we * bfhi(s0.w);
            acc[8] += we * bflo(s1.x); acc[9] += we * bfhi(s1.x);
        }
    }
    // quad butterfly: all 4 lanes of the node get full sums
    #pragma unroll
    for (int c = 0; c < 10; ++c) {
        acc[c] += __shfl_xor(acc[c], 1);
        acc[c] += __shfl_xor(acc[c], 2);
    }
    den += __shfl_xor(den, 1);
    den += __shfl_xor(den, 2);

    bool leader = active && (t == 0);
    float inv = 1.f / (den + 1e-16f);
    float vals[10];
    #pragma unroll
    for (int c = 0; c < 10; ++c)
        vals[c] = leader ? (acc[c] * inv + b2[c]) : 0.f;

    int lane = threadIdx.x & 63;
    int g0 = __shfl(g, 0);
    bool uniform = __all(g == g0 || g < 0);
    if (uniform) {
        if (g0 >= 0) {
            #pragma unroll
            for (int c = 0; c < 10; ++c) {
                float v = vals[c];
                for (int o = 32; o > 0; o >>= 1) v += __shfl_down(v, o);
                if (lane == 0) atomicAdd(&pooled[g0 * 10 + c], v);
            }
            float one = leader ? 1.f : 0.f;
            for (int o = 32; o > 0; o >>= 1) one += __shfl_down(one, o);
            if (lane == 0) atomicAdd(&cnt[g0], one);
        }
    } else if (leader) {
        #pragma unroll
        for (int c = 0; c < 10; ++c) atomicAdd(&pooled[g * 10 + c], vals[c]);
        atomicAdd(&cnt[g], 1.f);
    }
}

// ---------------- Final: mean + log_softmax ----------------
__global__ void final_kernel(const float* __restrict__ pooled,
                             const float* __restrict__ cnt, float* __restrict__ out)
{
    int g = threadIdx.x;
    if (g >= 64) return;
    float c = cnt[g];
    if (c < 1.f) c = 1.f;
    float v[10], m = -1e30f;
    #pragma unroll
    for (int i = 0; i < 10; ++i) {
        v[i] = pooled[g * 10 + i] / c;
        m = fmaxf(m, v[i]);
    }
    float s = 0.f;
    #pragma unroll
    for (int i = 0; i < 10; ++i) s += __expf(v[i] - m);
    float lse = m + logf(s);
    #pragma unroll
    for (int i = 0; i < 10; ++i) out[g * 10 + i] = v[i] - lse;
}

extern "C" void kernel_launch(void* const* d_in, const int* in_sizes, int n_in,
                              void* d_out, int out_size, void* d_ws, size_t ws_size,
                              hipStream_t stream) {
    const float* x       = (const float*)d_in[0];
    const int*   ei      = (const int*)  d_in[1];
    const int*   batch   = (const int*)  d_in[2];
    const float* W1      = (const float*)d_in[3];
    const float* a_src1  = (const float*)d_in[4];
    const float* a_dst1  = (const float*)d_in[5];
    const float* b1      = (const float*)d_in[6];
    const float* W2      = (const float*)d_in[7];
    const float* a_src2  = (const float*)d_in[8];
    const float* a_dst2  = (const float*)d_in[9];
    const float* b2      = (const float*)d_in[10];
    float* out = (float*)d_out;

    int N = in_sizes[0] / 128;
    int E = in_sizes[1] / 2;
    int NBK = (N + BWIDTH - 1) >> BSHIFT;

    float* f = (float*)d_ws;
    size_t off = 0;
    unsigned short* h1b = (unsigned short*)(f + off); off += (size_t)N * 32;  // N*64 bf16
    float* s1s  = f + off; off += (size_t)N * 4;
    float* s1d  = f + off; off += (size_t)N * 4;
    // time-aliased: pairs (E ints, live A3..scat) then h2p (N*16 bf16, agg1..agg2)
    unsigned short* h2p = (unsigned short*)(f + off);
    int*  pairs = (int*)(f + off);
    size_t r1 = ((size_t)N * 8 > (size_t)E) ? (size_t)N * 8 : (size_t)E;
    off += r1;
    int* iw = (int*)(f + off);
    size_t ioff = 0;
    int* offs    = iw + ioff; ioff += (size_t)N + 1;
    int* csr_src = iw + ioff; ioff += (size_t)E;
    int* bb      = iw + ioff; ioff += (size_t)NBK + 1;
    int* bcur    = iw + ioff; ioff += (size_t)NBK;
    int*   bhist  = iw + ioff;
    float* pooled = (float*)(iw + ioff + NBK);
    float* cnt    = pooled + 640;

    hipMemsetAsync((void*)bhist, 0, ((size_t)NBK + 704) * sizeof(int), stream);

    int g1_blocks = (N + G1_TN - 1) / G1_TN;
    gemm1_kernel<<<g1_blocks, 256, 0, stream>>>(x, W1, a_src1, a_dst1, h1b, s1s, s1d, N);

    bhist_kernel<<<256, 256, 0, stream>>>(ei, bhist, E, NBK);
    bscan_kernel<<<1, 1024, 0, stream>>>(bhist, bb, bcur, NBK);
    int ntiles = (E + A3_TILE - 1) / A3_TILE;
    partition_kernel<<<ntiles, 256, 0, stream>>>(ei, bcur, pairs, E, NBK);
    offs_kernel<<<NBK, 128, 0, stream>>>(pairs, bb, offs, N, NBK, E);
    scat_kernel<<<NBK, 128, 0, stream>>>(pairs, bb, offs, csr_src, N);

    agg1_kernel<<<(N * 8 + 255) / 256, 256, 0, stream>>>(
        offs, csr_src, h1b, s1s, s1d, b1, W2, a_src2, a_dst2, h2p, N);

    agg2_pool_kernel<<<(N * 4 + 255) / 256, 256, 0, stream>>>(
        offs, csr_src, h2p, b2, batch, pooled, cnt, N);

    final_kernel<<<1, 64, 0, stream>>>(pooled, cnt, out);
}